// Round 2
// baseline (215.766 us; speedup 1.0000x reference)
//
#include <hip/hip_runtime.h>

// Problem constants (reference: B=16, Q=2048, K=2048, D=128, fp32, NEG=-1e6)
constexpr int NB = 16;
constexpr int NQ = 2048;
constexpr int NK = 2048;
constexpr int ND = 128;
constexpr int QBLK = 64;   // q-rows per block (16 per wave)
constexpr int KVBLK = 32;  // kv per tile
constexpr float SCALE = 0.08838834764831844f; // 1/sqrt(128)

typedef __attribute__((ext_vector_type(4))) float f4;
typedef __attribute__((ext_vector_type(8))) unsigned short us8;
typedef __attribute__((ext_vector_type(8))) __bf16 bf16x8;

static __device__ __forceinline__ unsigned short f2bf(float f) {
    unsigned u = __builtin_bit_cast(unsigned, f);
    u += 0x7fffu + ((u >> 16) & 1u);
    return (unsigned short)(u >> 16);
}

static __device__ __forceinline__ f4 splat4(float x) {
    f4 r = {x, x, x, x};
    return r;
}

// ---------------------------------------------------------------------------
// Prep: K fp32 -> bf16 row-major [b][n][d]; V fp32 -> bf16 transposed [b][d][n]
// grid (NK/64, NB), 256 threads
// ---------------------------------------------------------------------------
__global__ __launch_bounds__(256)
void prep_kv(const float* __restrict__ kg, const float* __restrict__ vg,
             unsigned short* __restrict__ wk, unsigned short* __restrict__ wvt)
{
    const int b  = blockIdx.y;
    const int n0 = blockIdx.x * 64;
    const int t  = threadIdx.x;

    __shared__ __align__(16) unsigned short vt_l[128 * 72];

    // ---- K: straight convert, coalesced both ways
    {
        const int n  = n0 + (t >> 2);
        const int d0 = (t & 3) * 32;
        const float* gp = kg + (size_t)(b * NK + n) * ND + d0;
        unsigned short* op = wk + (size_t)(b * NK + n) * ND + d0;
        #pragma unroll
        for (int c = 0; c < 4; ++c) {
            f4 f0 = *(const f4*)(gp + c * 8);
            f4 f1 = *(const f4*)(gp + c * 8 + 4);
            us8 w;
            #pragma unroll
            for (int i = 0; i < 4; ++i) { w[i] = f2bf(f0[i]); w[i + 4] = f2bf(f1[i]); }
            *(us8*)(op + c * 8) = w;
        }
    }
    // ---- V: read coalesced, transpose through LDS, write V^T rows coalesced
    {
        const int n  = n0 + (t >> 2);
        const int d0 = (t & 3) * 32;
        const float* gp = vg + (size_t)(b * NK + n) * ND + d0;
        #pragma unroll
        for (int i = 0; i < 32; ++i)
            vt_l[(d0 + i) * 72 + (n - n0)] = f2bf(gp[i]);
    }
    __syncthreads();
    {
        const int d  = t >> 1;
        const int nh = (t & 1) * 32;
        unsigned short* op = wvt + (size_t)(b * ND + d) * NK + n0 + nh;
        #pragma unroll
        for (int j = 0; j < 4; ++j)
            *(us8*)(op + j * 8) = *(const us8*)&vt_l[d * 72 + nh + j * 8];
    }
}

// ---------------------------------------------------------------------------
// Fused attention v2: no K/V staging, fragments straight from L2-resident
// bf16 buffers; no __syncthreads in the kv loop.
// ---------------------------------------------------------------------------
__global__ __launch_bounds__(256, 2)
void attn_fused2(const float* __restrict__ qg, const int* __restrict__ vlen,
                 const unsigned short* __restrict__ wk,
                 const unsigned short* __restrict__ wvt,
                 float* __restrict__ og)
{
    const int bid = blockIdx.x;
    const int qc  = bid >> 4;
    const int b   = (bid ^ (bid >> 5)) & 15;   // batch-interleave co-resident blocks
    const int q0  = qc * QBLK;

    const int tid  = threadIdx.x;
    const int wid  = tid >> 6;
    const int lane = tid & 63;
    const int lrow = lane & 15;
    const int lgrp = lane >> 4;

    const int L = vlen[b];
    const bool uniform = (L <= 0);
    const int Leff = uniform ? NK : L;
    const int ntiles = (Leff + KVBLK - 1) / KVBLK;

    // per-wave P transpose tile only
    __shared__ __align__(16) float pt[4][16 * 36];

    // ---- Q fragments, pre-scaled, bf16
    bf16x8 aq[4];
    {
        const float* qp = qg + (size_t)(b * NQ + q0 + wid * 16 + lrow) * ND + lgrp * 8;
        #pragma unroll
        for (int c = 0; c < 4; ++c) {
            f4 f0 = *(const f4*)(qp + c * 32);
            f4 f1 = *(const f4*)(qp + c * 32 + 4);
            us8 u;
            #pragma unroll
            for (int i = 0; i < 4; ++i) {
                u[i]     = f2bf(f0[i] * SCALE);
                u[i + 4] = f2bf(f1[i] * SCALE);
            }
            aq[c] = __builtin_bit_cast(bf16x8, u);
        }
    }

    const unsigned short* kb = wk  + (size_t)b * NK * ND;
    const unsigned short* vb = wvt + (size_t)b * ND * NK;

    float m_r[4], l_r[4];
    f4 accO[8];
    #pragma unroll
    for (int r = 0; r < 4; ++r) { m_r[r] = -__builtin_inff(); l_r[r] = 0.f; }
    #pragma unroll
    for (int dc = 0; dc < 8; ++dc) accO[dc] = splat4(0.f);

    // K fragment prefetch registers (8 x us8)
    us8 bk[8], bk2[8];
    {
        const unsigned short* kr = kb + (size_t)lrow * ND + lgrp * 8;
        #pragma unroll
        for (int c = 0; c < 4; ++c) {
            bk[c]     = *(const us8*)(kr + c * 32);
            bk[4 + c] = *(const us8*)(kr + 16 * ND + c * 32);
        }
    }

    for (int t = 0; t < ntiles; ++t) {
        const int kv0 = t * KVBLK;

        // ---- QK^T from prefetched fragments
        f4 s0 = splat4(0.f), s1 = splat4(0.f);
        #pragma unroll
        for (int c = 0; c < 4; ++c) {
            s0 = __builtin_amdgcn_mfma_f32_16x16x32_bf16(
                aq[c], __builtin_bit_cast(bf16x8, bk[c]), s0, 0, 0, 0);
            s1 = __builtin_amdgcn_mfma_f32_16x16x32_bf16(
                aq[c], __builtin_bit_cast(bf16x8, bk[4 + c]), s1, 0, 0, 0);
        }

        // ---- issue next tile's K fragments (hidden under softmax + PV)
        {
            const int tn = (t + 1 < ntiles) ? (t + 1) : t;
            const unsigned short* kr = kb + (size_t)(tn * KVBLK + lrow) * ND + lgrp * 8;
            #pragma unroll
            for (int c = 0; c < 4; ++c) {
                bk2[c]     = *(const us8*)(kr + c * 32);
                bk2[4 + c] = *(const us8*)(kr + 16 * ND + c * 32);
            }
        }

        // ---- mask
        const int col0 = kv0 + lrow;
        if (uniform) {
            s0 = splat4(0.f);
            s1 = splat4(0.f);
        } else {
            if (col0 >= L)      s0 = splat4(-__builtin_inff());
            if (col0 + 16 >= L) s1 = splat4(-__builtin_inff());
        }

        // ---- online softmax
        float pm[4];
        #pragma unroll
        for (int r = 0; r < 4; ++r) pm[r] = fmaxf(s0[r], s1[r]);
        #pragma unroll
        for (int off = 8; off > 0; off >>= 1) {
            #pragma unroll
            for (int r = 0; r < 4; ++r)
                pm[r] = fmaxf(pm[r], __shfl_xor(pm[r], off));
        }
        float pr0[4], pr1[4], rs[4], sc[4];
        #pragma unroll
        for (int r = 0; r < 4; ++r) {
            float mn = fmaxf(m_r[r], pm[r]);
            sc[r]  = __expf(m_r[r] - mn);
            m_r[r] = mn;
            pr0[r] = __expf(s0[r] - mn);
            pr1[r] = __expf(s1[r] - mn);
            rs[r]  = pr0[r] + pr1[r];
        }
        #pragma unroll
        for (int off = 8; off > 0; off >>= 1) {
            #pragma unroll
            for (int r = 0; r < 4; ++r)
                rs[r] += __shfl_xor(rs[r], off);
        }
        #pragma unroll
        for (int r = 0; r < 4; ++r) l_r[r] = l_r[r] * sc[r] + rs[r];
        #pragma unroll
        for (int dc = 0; dc < 8; ++dc) {
            #pragma unroll
            for (int r = 0; r < 4; ++r) accO[dc][r] *= sc[r];
        }

        // ---- transpose P through per-wave LDS tile (wave-internal, no barrier)
        float* pw = pt[wid];
        #pragma unroll
        for (int r = 0; r < 4; ++r) {
            pw[(lgrp * 4 + r) * 36 + lrow]      = pr0[r];
            pw[(lgrp * 4 + r) * 36 + 16 + lrow] = pr1[r];
        }
        asm volatile("s_waitcnt lgkmcnt(0)" ::: "memory");
        f4 a0 = *(const f4*)&pw[lrow * 36 + lgrp * 8];
        f4 a1 = *(const f4*)&pw[lrow * 36 + lgrp * 8 + 4];
        us8 au;
        #pragma unroll
        for (int i = 0; i < 4; ++i) { au[i] = f2bf(a0[i]); au[i + 4] = f2bf(a1[i]); }
        bf16x8 ap = __builtin_bit_cast(bf16x8, au);

        // ---- PV: B-fragments straight from V^T (L2-resident)
        #pragma unroll
        for (int dc = 0; dc < 8; ++dc) {
            bf16x8 bv = __builtin_bit_cast(bf16x8,
                *(const us8*)(vb + (size_t)(dc * 16 + lrow) * NK + kv0 + lgrp * 8));
            accO[dc] = __builtin_amdgcn_mfma_f32_16x16x32_bf16(ap, bv, accO[dc], 0, 0, 0);
        }

        #pragma unroll
        for (int c = 0; c < 8; ++c) bk[c] = bk2[c];
    }

    // ---- epilogue
    float inv[4];
    #pragma unroll
    for (int r = 0; r < 4; ++r) inv[r] = 1.0f / l_r[r];
    float* op = og + (size_t)(b * NQ + q0 + wid * 16) * ND;
    #pragma unroll
    for (int dc = 0; dc < 8; ++dc) {
        #pragma unroll
        for (int r = 0; r < 4; ++r)
            op[(lgrp * 4 + r) * ND + dc * 16 + lrow] = accO[dc][r] * inv[r];
    }
}

// ---------------------------------------------------------------------------
// Fallback (R1 kernel): used only if ws_size < 16 MB
// ---------------------------------------------------------------------------
__global__ __launch_bounds__(256, 2)
void attn_fused(const float* __restrict__ qg, const float* __restrict__ kg,
                const float* __restrict__ vg, const int* __restrict__ vlen,
                float* __restrict__ og)
{
    const int b    = blockIdx.y;
    const int q0   = blockIdx.x * QBLK;
    const int tid  = threadIdx.x;
    const int wid  = tid >> 6;
    const int lane = tid & 63;
    const int lrow = lane & 15;
    const int lgrp = lane >> 4;

    const int L = vlen[b];
    const bool uniform = (L <= 0);
    const int Leff = uniform ? NK : L;
    const int ntiles = (Leff + KVBLK - 1) / KVBLK;

    __shared__ __align__(16) unsigned short kt[32 * 136];
    __shared__ __align__(16) unsigned short vt[128 * 40];
    __shared__ __align__(16) float pt[4][16 * 36];

    bf16x8 aq[4];
    {
        const float* qp = qg + (size_t)(b * NQ + q0 + wid * 16 + lrow) * ND + lgrp * 8;
        #pragma unroll
        for (int c = 0; c < 4; ++c) {
            f4 f0 = *(const f4*)(qp + c * 32);
            f4 f1 = *(const f4*)(qp + c * 32 + 4);
            us8 u;
            #pragma unroll
            for (int i = 0; i < 4; ++i) {
                u[i]     = f2bf(f0[i] * SCALE);
                u[i + 4] = f2bf(f1[i] * SCALE);
            }
            aq[c] = __builtin_bit_cast(bf16x8, u);
        }
    }

    float m_r[4], l_r[4];
    f4 accO[8];
    #pragma unroll
    for (int r = 0; r < 4; ++r) { m_r[r] = -__builtin_inff(); l_r[r] = 0.f; }
    #pragma unroll
    for (int dc = 0; dc < 8; ++dc) accO[dc] = splat4(0.f);

    for (int t = 0; t < ntiles; ++t) {
        const int kv0 = t * KVBLK;
        __syncthreads();
        {
            const int r  = tid >> 3;
            const int c0 = (tid & 7) * 16;
            const float* gp = kg + (size_t)(b * NK + kv0 + r) * ND + c0;
            f4 f0 = *(const f4*)(gp);
            f4 f1 = *(const f4*)(gp + 4);
            f4 f2 = *(const f4*)(gp + 8);
            f4 f3 = *(const f4*)(gp + 12);
            us8 w0, w1;
            #pragma unroll
            for (int i = 0; i < 4; ++i) {
                w0[i]     = f2bf(f0[i]);
                w0[i + 4] = f2bf(f1[i]);
                w1[i]     = f2bf(f2[i]);
                w1[i + 4] = f2bf(f3[i]);
            }
            unsigned short* dst = &kt[r * 136 + c0];
            *(us8*)(dst)     = w0;
            *(us8*)(dst + 8) = w1;
        }
        {
            const int d  = tid & 127;
            const int g2 = tid >> 7;
            const float* gp = vg + (size_t)(b * NK + kv0 + g2 * 16) * ND + d;
            us8 w0, w1;
            #pragma unroll
            for (int j = 0; j < 8; ++j) {
                w0[j] = f2bf(gp[(size_t)j * ND]);
                w1[j] = f2bf(gp[(size_t)(j + 8) * ND]);
            }
            unsigned short* dst = &vt[d * 40 + g2 * 16];
            *(us8*)(dst)     = w0;
            *(us8*)(dst + 8) = w1;
        }
        __syncthreads();

        f4 s0 = splat4(0.f), s1 = splat4(0.f);
        #pragma unroll
        for (int c = 0; c < 4; ++c) {
            bf16x8 bk0 = __builtin_bit_cast(bf16x8,
                *(const us8*)&kt[lrow * 136 + c * 32 + lgrp * 8]);
            s0 = __builtin_amdgcn_mfma_f32_16x16x32_bf16(aq[c], bk0, s0, 0, 0, 0);
            bf16x8 bk1 = __builtin_bit_cast(bf16x8,
                *(const us8*)&kt[(16 + lrow) * 136 + c * 32 + lgrp * 8]);
            s1 = __builtin_amdgcn_mfma_f32_16x16x32_bf16(aq[c], bk1, s1, 0, 0, 0);
        }

        const int col0 = kv0 + lrow;
        if (uniform) {
            s0 = splat4(0.f);
            s1 = splat4(0.f);
        } else {
            if (col0 >= L)      s0 = splat4(-__builtin_inff());
            if (col0 + 16 >= L) s1 = splat4(-__builtin_inff());
        }

        float pm[4];
        #pragma unroll
        for (int r = 0; r < 4; ++r) pm[r] = fmaxf(s0[r], s1[r]);
        #pragma unroll
        for (int off = 8; off > 0; off >>= 1) {
            #pragma unroll
            for (int r = 0; r < 4; ++r)
                pm[r] = fmaxf(pm[r], __shfl_xor(pm[r], off));
        }
        float pr0[4], pr1[4], rs[4], sc[4];
        #pragma unroll
        for (int r = 0; r < 4; ++r) {
            float mn = fmaxf(m_r[r], pm[r]);
            sc[r]  = __expf(m_r[r] - mn);
            m_r[r] = mn;
            pr0[r] = __expf(s0[r] - mn);
            pr1[r] = __expf(s1[r] - mn);
            rs[r]  = pr0[r] + pr1[r];
        }
        #pragma unroll
        for (int off = 8; off > 0; off >>= 1) {
            #pragma unroll
            for (int r = 0; r < 4; ++r)
                rs[r] += __shfl_xor(rs[r], off);
        }
        #pragma unroll
        for (int r = 0; r < 4; ++r) l_r[r] = l_r[r] * sc[r] + rs[r];
        #pragma unroll
        for (int dc = 0; dc < 8; ++dc) {
            #pragma unroll
            for (int r = 0; r < 4; ++r) accO[dc][r] *= sc[r];
        }

        float* pw = pt[wid];
        #pragma unroll
        for (int r = 0; r < 4; ++r) {
            pw[(lgrp * 4 + r) * 36 + lrow]      = pr0[r];
            pw[(lgrp * 4 + r) * 36 + 16 + lrow] = pr1[r];
        }
        asm volatile("s_waitcnt lgkmcnt(0)" ::: "memory");
        f4 a0 = *(const f4*)&pw[lrow * 36 + lgrp * 8];
        f4 a1 = *(const f4*)&pw[lrow * 36 + lgrp * 8 + 4];
        us8 au;
        #pragma unroll
        for (int i = 0; i < 4; ++i) { au[i] = f2bf(a0[i]); au[i + 4] = f2bf(a1[i]); }
        bf16x8 ap = __builtin_bit_cast(bf16x8, au);

        #pragma unroll
        for (int dc = 0; dc < 8; ++dc) {
            bf16x8 bv = __builtin_bit_cast(bf16x8,
                *(const us8*)&vt[(dc * 16 + lrow) * 40 + lgrp * 8]);
            accO[dc] = __builtin_amdgcn_mfma_f32_16x16x32_bf16(ap, bv, accO[dc], 0, 0, 0);
        }
    }

    float inv[4];
    #pragma unroll
    for (int r = 0; r < 4; ++r) inv[r] = 1.0f / l_r[r];
    float* op = og + (size_t)(b * NQ + q0 + wid * 16) * ND;
    #pragma unroll
    for (int dc = 0; dc < 8; ++dc) {
        #pragma unroll
        for (int r = 0; r < 4; ++r)
            op[(lgrp * 4 + r) * ND + dc * 16 + lrow] = accO[dc][r] * inv[r];
    }
}

extern "C" void kernel_launch(void* const* d_in, const int* in_sizes, int n_in,
                              void* d_out, int out_size, void* d_ws, size_t ws_size,
                              hipStream_t stream) {
    (void)in_sizes; (void)n_in; (void)out_size;
    const float* q  = (const float*)d_in[0];
    const float* k  = (const float*)d_in[1];
    const float* v  = (const float*)d_in[2];
    const int*   vl = (const int*)d_in[3];
    float* out = (float*)d_out;

    const size_t half = (size_t)NB * NK * ND * sizeof(unsigned short); // 8 MB
    if (ws_size >= 2 * half) {
        unsigned short* wk  = (unsigned short*)d_ws;
        unsigned short* wvt = wk + (size_t)NB * NK * ND;
        hipLaunchKernelGGL(prep_kv, dim3(NK / 64, NB), dim3(256), 0, stream, k, v, wk, wvt);
        hipLaunchKernelGGL(attn_fused2, dim3(NQ / QBLK * NB), dim3(256), 0, stream,
                           q, vl, wk, wvt, out);
    } else {
        hipLaunchKernelGGL(attn_fused, dim3(NQ / QBLK, NB), dim3(256), 0, stream,
                           q, k, v, vl, out);
    }
}

// Round 3
// 124.290 us; speedup vs baseline: 1.7360x; 1.7360x over previous
//
#include <hip/hip_runtime.h>

// Problem constants (reference: B=16, Q=2048, K=2048, D=128, fp32, NEG=-1e6)
constexpr int NB = 16;
constexpr int NQ = 2048;
constexpr int NK = 2048;
constexpr int ND = 128;
constexpr int QBLK = 64;   // q-rows per block (16 per wave)
constexpr int KVBLK = 64;  // kv per tile (32 tiles per batch)
constexpr int NTILE = NK / KVBLK;         // 32
constexpr int TILE_USH = KVBLK * ND;      // 8192 ushorts = 16KB per tile
constexpr float SCALE = 0.08838834764831844f; // 1/sqrt(128)

typedef __attribute__((ext_vector_type(4))) float f4;
typedef __attribute__((ext_vector_type(8))) unsigned short us8;
typedef __attribute__((ext_vector_type(8))) __bf16 bf16x8;

static __device__ __forceinline__ unsigned short f2bf(float f) {
    unsigned u = __builtin_bit_cast(unsigned, f);
    u += 0x7fffu + ((u >> 16) & 1u);
    return (unsigned short)(u >> 16);
}
static __device__ __forceinline__ f4 splat4(float x) { f4 r = {x,x,x,x}; return r; }

// ---------------------------------------------------------------------------
// Prep: per (batch, kv-tile) write K and V^T in MFMA-fragment-linear order.
// K tile element (kv,d)  -> ushort off (h*4+c)*512 + lr*32 + lg*8 + j
//      h=kv>>4, lr=kv&15, c=d>>5, lg=(d>>3)&3, j=d&7
// V^T tile element (d,kv)-> ushort off (dc*2+hh)*512 + lr*32 + lg*8 + j
//      dc=d>>4, lr=d&15, hh=kv>>5, lg=(kv>>3)&3, j=kv&7
// Every attention fragment load becomes a wave-contiguous 1KB read.
// grid (NTILE, NB), 256 threads
// ---------------------------------------------------------------------------
__global__ __launch_bounds__(256)
void prep_kv2(const float* __restrict__ kg, const float* __restrict__ vg,
              unsigned short* __restrict__ wk, unsigned short* __restrict__ wvt)
{
    const int b   = blockIdx.y;
    const int t   = blockIdx.x;
    const int kv0 = t * KVBLK;
    const int t0  = threadIdx.x;

    __shared__ __align__(16) unsigned short vl[64 * 136];

    // ---- K: coalesced read, fragment-linear coalesced write
    {
        const int kv = t0 >> 2;
        const int c  = t0 & 3;
        const int d0 = c * 32;
        const int h  = kv >> 4, lr = kv & 15;
        const float* gp = kg + (size_t)(b * NK + kv0 + kv) * ND + d0;
        unsigned short* ob = wk + (size_t)(b * NTILE + t) * TILE_USH
                                + (h * 4 + c) * 512 + lr * 32;
        #pragma unroll
        for (int g = 0; g < 4; ++g) {
            f4 f0 = *(const f4*)(gp + g * 8);
            f4 f1 = *(const f4*)(gp + g * 8 + 4);
            us8 w;
            #pragma unroll
            for (int i = 0; i < 4; ++i) { w[i] = f2bf(f0[i]); w[i+4] = f2bf(f1[i]); }
            *(us8*)(ob + g * 8) = w;
        }
    }
    // ---- V: coalesced read -> LDS [64 kv][136 d]
    {
        const int kv = t0 >> 2;
        const int d0 = (t0 & 3) * 32;
        const float* gp = vg + (size_t)(b * NK + kv0 + kv) * ND + d0;
        unsigned short* lb = &vl[kv * 136 + d0];
        #pragma unroll
        for (int g = 0; g < 4; ++g) {
            f4 f0 = *(const f4*)(gp + g * 8);
            f4 f1 = *(const f4*)(gp + g * 8 + 4);
            us8 w;
            #pragma unroll
            for (int i = 0; i < 4; ++i) { w[i] = f2bf(f0[i]); w[i+4] = f2bf(f1[i]); }
            *(us8*)(lb + g * 8) = w;
        }
    }
    __syncthreads();
    // ---- V^T out: fragment-linear, fully coalesced 16B/thread writes
    {
        unsigned short* ob = wvt + (size_t)(b * NTILE + t) * TILE_USH;
        #pragma unroll
        for (int iter = 0; iter < 4; ++iter) {
            const int cid = iter * 256 + t0;     // 16B chunk id, 0..1023
            const int dch = cid >> 6;            // dc*2+hh
            const int lr  = (cid >> 2) & 15;
            const int lg  = cid & 3;
            const int d   = (dch >> 1) * 16 + lr;
            const int kvb = (dch & 1) * 32 + lg * 8;
            us8 w;
            #pragma unroll
            for (int j = 0; j < 8; ++j) w[j] = vl[(kvb + j) * 136 + d];
            *(us8*)(ob + cid * 8) = w;
        }
    }
}

// ---------------------------------------------------------------------------
// Fused attention v3: fragment-linear global loads (1KB/wave/instr), XCD
// batch affinity (2 batches -> one XCD's 4MB L2), KVBLK=64, reg prefetch,
// no barriers in kv loop.
// ---------------------------------------------------------------------------
__global__ __launch_bounds__(256, 2)
void attn_fused3(const float* __restrict__ qg, const int* __restrict__ vlen,
                 const unsigned short* __restrict__ wk,
                 const unsigned short* __restrict__ wvt,
                 float* __restrict__ og)
{
    const int bid = blockIdx.x;
    // XCD affinity: bid%8 -> XCD (round-robin dispatch); batches 2x,2x+1 on XCD x
    const int b  = ((bid & 7) << 1) | ((bid >> 3) & 1);
    const int qc = bid >> 4;
    const int q0 = qc * QBLK;

    const int tid  = threadIdx.x;
    const int wid  = tid >> 6;
    const int lane = tid & 63;
    const int lrow = lane & 15;
    const int lgrp = lane >> 4;

    const int L = vlen[b];
    const bool uniform = (L <= 0);
    const int Leff = uniform ? NK : L;
    const int ntiles = (Leff + KVBLK - 1) / KVBLK;

    // per-wave P transpose tile: 16 rows x 64 f32, stride 68 (272B)
    __shared__ __align__(16) float pt[4][16 * 68];

    // ---- Q fragments, pre-scaled, bf16
    bf16x8 aq[4];
    {
        const float* qp = qg + (size_t)(b * NQ + q0 + wid * 16 + lrow) * ND + lgrp * 8;
        #pragma unroll
        for (int c = 0; c < 4; ++c) {
            f4 f0 = *(const f4*)(qp + c * 32);
            f4 f1 = *(const f4*)(qp + c * 32 + 4);
            us8 u;
            #pragma unroll
            for (int i = 0; i < 4; ++i) {
                u[i]     = f2bf(f0[i] * SCALE);
                u[i + 4] = f2bf(f1[i] * SCALE);
            }
            aq[c] = __builtin_bit_cast(bf16x8, u);
        }
    }

    const unsigned short* kb = wk  + (size_t)b * NTILE * TILE_USH;
    const unsigned short* vb = wvt + (size_t)b * NTILE * TILE_USH;
    const int fragoff = lrow * 32 + lgrp * 8;   // ushort offset of this lane in a fragment

    float m_r[4], l_r[4];
    f4 accO[8];
    #pragma unroll
    for (int r = 0; r < 4; ++r) { m_r[r] = -__builtin_inff(); l_r[r] = 0.f; }
    #pragma unroll
    for (int dc = 0; dc < 8; ++dc) accO[dc] = splat4(0.f);

    us8 kf[16], vf[16];
    {
        const unsigned short* p = kb + fragoff;
        #pragma unroll
        for (int f = 0; f < 16; ++f) kf[f] = *(const us8*)(p + f * 512);
    }

    for (int t = 0; t < ntiles; ++t) {
        const int kv0 = t * KVBLK;

        // ---- issue V(t) fragment loads (latency hidden under softmax)
        {
            const unsigned short* p = vb + (size_t)t * TILE_USH + fragoff;
            #pragma unroll
            for (int f = 0; f < 16; ++f) vf[f] = *(const us8*)(p + f * 512);
        }

        // ---- QK^T from prefetched K fragments: S[16q x 64kv]
        f4 s[4];
        #pragma unroll
        for (int h = 0; h < 4; ++h) s[h] = splat4(0.f);
        #pragma unroll
        for (int h = 0; h < 4; ++h)
            #pragma unroll
            for (int c = 0; c < 4; ++c)
                s[h] = __builtin_amdgcn_mfma_f32_16x16x32_bf16(
                    aq[c], __builtin_bit_cast(bf16x8, kf[h * 4 + c]), s[h], 0, 0, 0);

        // ---- issue K(t+1) fragment loads (hidden under softmax + PV)
        {
            const int tn = (t + 1 < ntiles) ? (t + 1) : t;
            const unsigned short* p = kb + (size_t)tn * TILE_USH + fragoff;
            #pragma unroll
            for (int f = 0; f < 16; ++f) kf[f] = *(const us8*)(p + f * 512);
        }

        // ---- mask
        if (uniform) {
            #pragma unroll
            for (int h = 0; h < 4; ++h) s[h] = splat4(0.f);
        } else {
            #pragma unroll
            for (int h = 0; h < 4; ++h)
                if (kv0 + h * 16 + lrow >= L) s[h] = splat4(-__builtin_inff());
        }

        // ---- online softmax (rows q = lgrp*4+r; reduce across 16 col-lanes)
        float pm[4];
        #pragma unroll
        for (int r = 0; r < 4; ++r)
            pm[r] = fmaxf(fmaxf(s[0][r], s[1][r]), fmaxf(s[2][r], s[3][r]));
        #pragma unroll
        for (int off = 8; off > 0; off >>= 1) {
            #pragma unroll
            for (int r = 0; r < 4; ++r)
                pm[r] = fmaxf(pm[r], __shfl_xor(pm[r], off));
        }
        float pr[4][4], rs[4], sc[4];
        #pragma unroll
        for (int r = 0; r < 4; ++r) {
            float mn = fmaxf(m_r[r], pm[r]);
            sc[r]  = __expf(m_r[r] - mn);
            m_r[r] = mn;
            rs[r] = 0.f;
            #pragma unroll
            for (int h = 0; h < 4; ++h) {
                pr[h][r] = __expf(s[h][r] - mn);
                rs[r] += pr[h][r];
            }
        }
        #pragma unroll
        for (int off = 8; off > 0; off >>= 1) {
            #pragma unroll
            for (int r = 0; r < 4; ++r)
                rs[r] += __shfl_xor(rs[r], off);
        }
        #pragma unroll
        for (int r = 0; r < 4; ++r) l_r[r] = l_r[r] * sc[r] + rs[r];
        #pragma unroll
        for (int dc = 0; dc < 8; ++dc) {
            #pragma unroll
            for (int r = 0; r < 4; ++r) accO[dc][r] *= sc[r];
        }

        // ---- transpose P (C-layout -> A-frag) via per-wave LDS tile
        float* pw = pt[wid];
        #pragma unroll
        for (int h = 0; h < 4; ++h)
            #pragma unroll
            for (int r = 0; r < 4; ++r)
                pw[(lgrp * 4 + r) * 68 + h * 16 + lrow] = pr[h][r];
        asm volatile("s_waitcnt lgkmcnt(0)" ::: "memory");
        f4 a0 = *(const f4*)&pw[lrow * 68 + lgrp * 8];
        f4 a1 = *(const f4*)&pw[lrow * 68 + lgrp * 8 + 4];
        f4 a2 = *(const f4*)&pw[lrow * 68 + 32 + lgrp * 8];
        f4 a3 = *(const f4*)&pw[lrow * 68 + 32 + lgrp * 8 + 4];
        us8 u0, u1;
        #pragma unroll
        for (int i = 0; i < 4; ++i) {
            u0[i] = f2bf(a0[i]); u0[i + 4] = f2bf(a1[i]);
            u1[i] = f2bf(a2[i]); u1[i + 4] = f2bf(a3[i]);
        }
        bf16x8 ap0 = __builtin_bit_cast(bf16x8, u0);
        bf16x8 ap1 = __builtin_bit_cast(bf16x8, u1);

        // ---- PV: O[16q x 128d] += P(16x64) . V(64x128)
        #pragma unroll
        for (int dc = 0; dc < 8; ++dc) {
            accO[dc] = __builtin_amdgcn_mfma_f32_16x16x32_bf16(
                ap0, __builtin_bit_cast(bf16x8, vf[dc * 2]), accO[dc], 0, 0, 0);
            accO[dc] = __builtin_amdgcn_mfma_f32_16x16x32_bf16(
                ap1, __builtin_bit_cast(bf16x8, vf[dc * 2 + 1]), accO[dc], 0, 0, 0);
        }
    }

    // ---- epilogue
    float inv[4];
    #pragma unroll
    for (int r = 0; r < 4; ++r) inv[r] = 1.0f / l_r[r];
    float* op = og + (size_t)(b * NQ + q0 + wid * 16) * ND;
    #pragma unroll
    for (int dc = 0; dc < 8; ++dc) {
        #pragma unroll
        for (int r = 0; r < 4; ++r)
            op[(lgrp * 4 + r) * ND + dc * 16 + lrow] = accO[dc][r] * inv[r];
    }
}

// ---------------------------------------------------------------------------
// Fallback (R1 kernel): used only if ws_size < 16 MB
// ---------------------------------------------------------------------------
__global__ __launch_bounds__(256, 2)
void attn_fused(const float* __restrict__ qg, const float* __restrict__ kg,
                const float* __restrict__ vg, const int* __restrict__ vlen,
                float* __restrict__ og)
{
    const int b    = blockIdx.y;
    const int q0   = blockIdx.x * QBLK;
    const int tid  = threadIdx.x;
    const int wid  = tid >> 6;
    const int lane = tid & 63;
    const int lrow = lane & 15;
    const int lgrp = lane >> 4;

    const int L = vlen[b];
    const bool uniform = (L <= 0);
    const int Leff = uniform ? NK : L;
    const int nt32 = (Leff + 31) / 32;

    __shared__ __align__(16) unsigned short kt[32 * 136];
    __shared__ __align__(16) unsigned short vt[128 * 40];
    __shared__ __align__(16) float pt[4][16 * 36];

    bf16x8 aq[4];
    {
        const float* qp = qg + (size_t)(b * NQ + q0 + wid * 16 + lrow) * ND + lgrp * 8;
        #pragma unroll
        for (int c = 0; c < 4; ++c) {
            f4 f0 = *(const f4*)(qp + c * 32);
            f4 f1 = *(const f4*)(qp + c * 32 + 4);
            us8 u;
            #pragma unroll
            for (int i = 0; i < 4; ++i) {
                u[i]     = f2bf(f0[i] * SCALE);
                u[i + 4] = f2bf(f1[i] * SCALE);
            }
            aq[c] = __builtin_bit_cast(bf16x8, u);
        }
    }

    float m_r[4], l_r[4];
    f4 accO[8];
    #pragma unroll
    for (int r = 0; r < 4; ++r) { m_r[r] = -__builtin_inff(); l_r[r] = 0.f; }
    #pragma unroll
    for (int dc = 0; dc < 8; ++dc) accO[dc] = splat4(0.f);

    for (int t = 0; t < nt32; ++t) {
        const int kv0 = t * 32;
        __syncthreads();
        {
            const int r  = tid >> 3;
            const int c0 = (tid & 7) * 16;
            const float* gp = kg + (size_t)(b * NK + kv0 + r) * ND + c0;
            f4 f0 = *(const f4*)(gp);
            f4 f1 = *(const f4*)(gp + 4);
            f4 f2 = *(const f4*)(gp + 8);
            f4 f3 = *(const f4*)(gp + 12);
            us8 w0, w1;
            #pragma unroll
            for (int i = 0; i < 4; ++i) {
                w0[i]     = f2bf(f0[i]);
                w0[i + 4] = f2bf(f1[i]);
                w1[i]     = f2bf(f2[i]);
                w1[i + 4] = f2bf(f3[i]);
            }
            unsigned short* dst = &kt[r * 136 + c0];
            *(us8*)(dst)     = w0;
            *(us8*)(dst + 8) = w1;
        }
        {
            const int d  = tid & 127;
            const int g2 = tid >> 7;
            const float* gp = vg + (size_t)(b * NK + kv0 + g2 * 16) * ND + d;
            us8 w0, w1;
            #pragma unroll
            for (int j = 0; j < 8; ++j) {
                w0[j] = f2bf(gp[(size_t)j * ND]);
                w1[j] = f2bf(gp[(size_t)(j + 8) * ND]);
            }
            unsigned short* dst = &vt[d * 40 + g2 * 16];
            *(us8*)(dst)     = w0;
            *(us8*)(dst + 8) = w1;
        }
        __syncthreads();

        f4 s0 = splat4(0.f), s1 = splat4(0.f);
        #pragma unroll
        for (int c = 0; c < 4; ++c) {
            bf16x8 bk0 = __builtin_bit_cast(bf16x8,
                *(const us8*)&kt[lrow * 136 + c * 32 + lgrp * 8]);
            s0 = __builtin_amdgcn_mfma_f32_16x16x32_bf16(aq[c], bk0, s0, 0, 0, 0);
            bf16x8 bk1 = __builtin_bit_cast(bf16x8,
                *(const us8*)&kt[(16 + lrow) * 136 + c * 32 + lgrp * 8]);
            s1 = __builtin_amdgcn_mfma_f32_16x16x32_bf16(aq[c], bk1, s1, 0, 0, 0);
        }

        const int col0 = kv0 + lrow;
        if (uniform) {
            s0 = splat4(0.f);
            s1 = splat4(0.f);
        } else {
            if (col0 >= L)      s0 = splat4(-__builtin_inff());
            if (col0 + 16 >= L) s1 = splat4(-__builtin_inff());
        }

        float pm[4];
        #pragma unroll
        for (int r = 0; r < 4; ++r) pm[r] = fmaxf(s0[r], s1[r]);
        #pragma unroll
        for (int off = 8; off > 0; off >>= 1) {
            #pragma unroll
            for (int r = 0; r < 4; ++r)
                pm[r] = fmaxf(pm[r], __shfl_xor(pm[r], off));
        }
        float pr0[4], pr1[4], rs[4], sc[4];
        #pragma unroll
        for (int r = 0; r < 4; ++r) {
            float mn = fmaxf(m_r[r], pm[r]);
            sc[r]  = __expf(m_r[r] - mn);
            m_r[r] = mn;
            pr0[r] = __expf(s0[r] - mn);
            pr1[r] = __expf(s1[r] - mn);
            rs[r]  = pr0[r] + pr1[r];
        }
        #pragma unroll
        for (int off = 8; off > 0; off >>= 1) {
            #pragma unroll
            for (int r = 0; r < 4; ++r)
                rs[r] += __shfl_xor(rs[r], off);
        }
        #pragma unroll
        for (int r = 0; r < 4; ++r) l_r[r] = l_r[r] * sc[r] + rs[r];
        #pragma unroll
        for (int dc = 0; dc < 8; ++dc) {
            #pragma unroll
            for (int r = 0; r < 4; ++r) accO[dc][r] *= sc[r];
        }

        float* pw = pt[wid];
        #pragma unroll
        for (int r = 0; r < 4; ++r) {
            pw[(lgrp * 4 + r) * 36 + lrow]      = pr0[r];
            pw[(lgrp * 4 + r) * 36 + 16 + lrow] = pr1[r];
        }
        asm volatile("s_waitcnt lgkmcnt(0)" ::: "memory");
        f4 a0 = *(const f4*)&pw[lrow * 36 + lgrp * 8];
        f4 a1 = *(const f4*)&pw[lrow * 36 + lgrp * 8 + 4];
        us8 au;
        #pragma unroll
        for (int i = 0; i < 4; ++i) { au[i] = f2bf(a0[i]); au[i + 4] = f2bf(a1[i]); }
        bf16x8 ap = __builtin_bit_cast(bf16x8, au);

        #pragma unroll
        for (int dc = 0; dc < 8; ++dc) {
            bf16x8 bv = __builtin_bit_cast(bf16x8,
                *(const us8*)&vt[(dc * 16 + lrow) * 40 + lgrp * 8]);
            accO[dc] = __builtin_amdgcn_mfma_f32_16x16x32_bf16(ap, bv, accO[dc], 0, 0, 0);
        }
    }

    float inv[4];
    #pragma unroll
    for (int r = 0; r < 4; ++r) inv[r] = 1.0f / l_r[r];
    float* op = og + (size_t)(b * NQ + q0 + wid * 16) * ND;
    #pragma unroll
    for (int dc = 0; dc < 8; ++dc) {
        #pragma unroll
        for (int r = 0; r < 4; ++r)
            op[(lgrp * 4 + r) * ND + dc * 16 + lrow] = accO[dc][r] * inv[r];
    }
}

extern "C" void kernel_launch(void* const* d_in, const int* in_sizes, int n_in,
                              void* d_out, int out_size, void* d_ws, size_t ws_size,
                              hipStream_t stream) {
    (void)in_sizes; (void)n_in; (void)out_size;
    const float* q  = (const float*)d_in[0];
    const float* k  = (const float*)d_in[1];
    const float* v  = (const float*)d_in[2];
    const int*   vl = (const int*)d_in[3];
    float* out = (float*)d_out;

    const size_t half = (size_t)NB * NK * ND * sizeof(unsigned short); // 8 MB
    if (ws_size >= 2 * half) {
        unsigned short* wk  = (unsigned short*)d_ws;
        unsigned short* wvt = wk + (size_t)NB * NK * ND;
        hipLaunchKernelGGL(prep_kv2, dim3(NTILE, NB), dim3(256), 0, stream, k, v, wk, wvt);
        hipLaunchKernelGGL(attn_fused3, dim3(NQ / QBLK * NB), dim3(256), 0, stream,
                           q, vl, wk, wvt, out);
    } else {
        hipLaunchKernelGGL(attn_fused, dim3(NQ / QBLK, NB), dim3(256), 0, stream,
                           q, k, v, vl, out);
    }
}

// Round 4
// 85.194 us; speedup vs baseline: 2.5327x; 1.4589x over previous
//
#include <hip/hip_runtime.h>

// Problem constants (reference: B=16, Q=2048, K=2048, D=128, fp32, NEG=-1e6)
constexpr int NB = 16;
constexpr int NQ = 2048;
constexpr int NK = 2048;
constexpr int ND = 128;
constexpr int QBLK = 64;   // q-rows per block (16 per wave)
constexpr int KVBLK = 64;  // kv per tile (32 tiles per batch)
constexpr int NTILE = NK / KVBLK;         // 32
constexpr int TILE_USH = KVBLK * ND;      // 8192 ushorts = 16KB per tile
constexpr float SCALE = 0.08838834764831844f; // 1/sqrt(128)

typedef __attribute__((ext_vector_type(4))) float f4;
typedef __attribute__((ext_vector_type(8))) unsigned short us8;
typedef __attribute__((ext_vector_type(8))) __bf16 bf16x8;

static __device__ __forceinline__ unsigned short f2bf(float f) {
    unsigned u = __builtin_bit_cast(unsigned, f);
    u += 0x7fffu + ((u >> 16) & 1u);
    return (unsigned short)(u >> 16);
}
static __device__ __forceinline__ f4 splat4(float x) { f4 r = {x,x,x,x}; return r; }

// async global->LDS DMA, 16B per lane; lds dest is wave-uniform base + lane*16
static __device__ __forceinline__ void load_lds16(const unsigned short* g, unsigned short* l) {
    __builtin_amdgcn_global_load_lds(
        (const __attribute__((address_space(1))) void*)g,
        (__attribute__((address_space(3))) void*)l,
        16, 0, 0);
}

// ---------------------------------------------------------------------------
// Prep: per (batch, kv-tile) write K and V^T in LANE-LINEAR fragment order:
//   K  element (kv,d): frag f=(kv>>4)*4+(d>>5); ushort off =
//        f*512 + ((d>>3)&3)*128 + (kv&15)*8 + (d&7)     (chunk index == lane)
//   V^T element (d,kv): frag f=(d>>4)*2+(kv>>5); ushort off =
//        f*512 + ((kv>>3)&3)*128 + (d&15)*8 + (kv&7)
// So global tile bytes == LDS tile bytes == ds_read addr (base + lane*16).
// grid (NTILE, NB), 256 threads
// ---------------------------------------------------------------------------
__global__ __launch_bounds__(256)
void prep_kv3(const float* __restrict__ kg, const float* __restrict__ vg,
              unsigned short* __restrict__ wk, unsigned short* __restrict__ wvt)
{
    const int b   = blockIdx.y;
    const int t   = blockIdx.x;
    const int kv0 = t * KVBLK;
    const int t0  = threadIdx.x;

    __shared__ __align__(16) unsigned short vl[64 * 136];

    // ---- K: coalesced read, fragment-lane-linear write
    {
        const int kv = t0 >> 2;
        const int c  = t0 & 3;
        const int d0 = c * 32;
        const int h  = kv >> 4, lr = kv & 15;
        const float* gp = kg + (size_t)(b * NK + kv0 + kv) * ND + d0;
        unsigned short* obase = wk + (size_t)(b * NTILE + t) * TILE_USH
                                   + (h * 4 + c) * 512 + lr * 8;
        #pragma unroll
        for (int g = 0; g < 4; ++g) {     // g = lane-group = (d>>3)&3
            f4 f0 = *(const f4*)(gp + g * 8);
            f4 f1 = *(const f4*)(gp + g * 8 + 4);
            us8 w;
            #pragma unroll
            for (int i = 0; i < 4; ++i) { w[i] = f2bf(f0[i]); w[i+4] = f2bf(f1[i]); }
            *(us8*)(obase + g * 128) = w;
        }
    }
    // ---- V: coalesced read -> LDS [64 kv][136 d]
    {
        const int kv = t0 >> 2;
        const int d0 = (t0 & 3) * 32;
        const float* gp = vg + (size_t)(b * NK + kv0 + kv) * ND + d0;
        unsigned short* lb = &vl[kv * 136 + d0];
        #pragma unroll
        for (int g = 0; g < 4; ++g) {
            f4 f0 = *(const f4*)(gp + g * 8);
            f4 f1 = *(const f4*)(gp + g * 8 + 4);
            us8 w;
            #pragma unroll
            for (int i = 0; i < 4; ++i) { w[i] = f2bf(f0[i]); w[i+4] = f2bf(f1[i]); }
            *(us8*)(lb + g * 8) = w;
        }
    }
    __syncthreads();
    // ---- V^T out: lane-linear chunks, fully coalesced 16B/thread writes
    {
        unsigned short* ob = wvt + (size_t)(b * NTILE + t) * TILE_USH;
        #pragma unroll
        for (int iter = 0; iter < 4; ++iter) {
            const int cid = iter * 256 + t0;   // chunk id 0..1023 (= f*64 + lane)
            const int f   = cid >> 6;
            const int l   = cid & 63;
            const int lg  = l >> 4, lr = l & 15;
            const int d   = (f >> 1) * 16 + lr;
            const int kvb = (f & 1) * 32 + lg * 8;
            us8 w;
            #pragma unroll
            for (int j = 0; j < 8; ++j) w[j] = vl[(kvb + j) * 136 + d];
            *(us8*)(ob + cid * 8) = w;
        }
    }
}

// ---------------------------------------------------------------------------
// Fused attention v4: LDS double-buffered K+V tiles staged once per block via
// global_load_lds (T3-minimum 2-phase), fragments via ds_read_b128.
// ---------------------------------------------------------------------------
__global__ __launch_bounds__(256, 2)
void attn_fused4(const float* __restrict__ qg, const int* __restrict__ vlen,
                 const unsigned short* __restrict__ wk,
                 const unsigned short* __restrict__ wvt,
                 float* __restrict__ og)
{
    const int bid = blockIdx.x;
    // XCD affinity: bid%8 -> XCD; batches 2x,2x+1 live on XCD x's L2
    const int b  = ((bid & 7) << 1) | ((bid >> 3) & 1);
    const int qc = bid >> 4;
    const int q0 = qc * QBLK;

    const int tid  = threadIdx.x;
    const int wid  = tid >> 6;
    const int lane = tid & 63;
    const int lrow = lane & 15;
    const int lgrp = lane >> 4;

    const int L = vlen[b];
    const bool uniform = (L <= 0);
    const int Leff = uniform ? NK : L;
    const int ntiles = (Leff + KVBLK - 1) / KVBLK;

    // double-buffered K+V tile: [buf][K 8192 ush | V 8192 ush] = 64 KB
    __shared__ __align__(16) unsigned short kvbuf[2][2 * TILE_USH / 1]; // 2x16384
    // per-wave P transpose tile, bf16: 16 rows x 72 stride = 2304 B/wave
    __shared__ __align__(16) unsigned short ptb[4][16 * 72];

    // ---- Q fragments, pre-scaled, bf16
    bf16x8 aq[4];
    {
        const float* qp = qg + (size_t)(b * NQ + q0 + wid * 16 + lrow) * ND + lgrp * 8;
        #pragma unroll
        for (int c = 0; c < 4; ++c) {
            f4 f0 = *(const f4*)(qp + c * 32);
            f4 f1 = *(const f4*)(qp + c * 32 + 4);
            us8 u;
            #pragma unroll
            for (int i = 0; i < 4; ++i) {
                u[i]     = f2bf(f0[i] * SCALE);
                u[i + 4] = f2bf(f1[i] * SCALE);
            }
            aq[c] = __builtin_bit_cast(bf16x8, u);
        }
    }

    const unsigned short* kb = wk  + (size_t)b * NTILE * TILE_USH;
    const unsigned short* vb = wvt + (size_t)b * NTILE * TILE_USH;

    // wave's staging slice: half = K or V, sub = which 8KB of the 16KB half
    const int s_half = wid >> 1;          // 0: K, 1: V
    const int s_sub  = wid & 1;           // 0/1
    const int s_off  = s_sub * 4096 + lane * 8;   // ushort offset in half

    float m_r[4], l_r[4];
    f4 accO[8];
    #pragma unroll
    for (int r = 0; r < 4; ++r) { m_r[r] = -__builtin_inff(); l_r[r] = 0.f; }
    #pragma unroll
    for (int dc = 0; dc < 8; ++dc) accO[dc] = splat4(0.f);

    // ---- prologue: stage tile 0
    {
        const unsigned short* src = (s_half ? vb : kb) + s_off;
        unsigned short* dst = &kvbuf[0][s_half * 8192 + s_sub * 4096];
        #pragma unroll
        for (int j = 0; j < 8; ++j)
            load_lds16(src + j * 512, dst + j * 512);
    }
    __syncthreads();

    for (int t = 0; t < ntiles; ++t) {
        const int kv0 = t * KVBLK;
        const int cur = t & 1;
        const unsigned short* kl = &kvbuf[cur][0];
        const unsigned short* vl2 = &kvbuf[cur][8192];

        // ---- issue stage(t+1) into the other buffer (hidden under this tile)
        if (t + 1 < ntiles) {
            const unsigned short* src =
                (s_half ? vb : kb) + (size_t)(t + 1) * TILE_USH + s_off;
            unsigned short* dst = &kvbuf[cur ^ 1][s_half * 8192 + s_sub * 4096];
            #pragma unroll
            for (int j = 0; j < 8; ++j)
                load_lds16(src + j * 512, dst + j * 512);
        }

        // ---- QK^T from LDS: S[16q x 64kv]
        f4 s[4];
        #pragma unroll
        for (int h = 0; h < 4; ++h) s[h] = splat4(0.f);
        #pragma unroll
        for (int h = 0; h < 4; ++h)
            #pragma unroll
            for (int c = 0; c < 4; ++c) {
                bf16x8 bk = __builtin_bit_cast(bf16x8,
                    *(const us8*)&kl[(h * 4 + c) * 512 + lane * 8]);
                s[h] = __builtin_amdgcn_mfma_f32_16x16x32_bf16(aq[c], bk, s[h], 0, 0, 0);
            }

        // ---- mask
        if (uniform) {
            #pragma unroll
            for (int h = 0; h < 4; ++h) s[h] = splat4(0.f);
        } else {
            #pragma unroll
            for (int h = 0; h < 4; ++h)
                if (kv0 + h * 16 + lrow >= L) s[h] = splat4(-__builtin_inff());
        }

        // ---- online softmax (rows q = lgrp*4+r; reduce across 16 col-lanes)
        float pm[4];
        #pragma unroll
        for (int r = 0; r < 4; ++r)
            pm[r] = fmaxf(fmaxf(s[0][r], s[1][r]), fmaxf(s[2][r], s[3][r]));
        #pragma unroll
        for (int off = 8; off > 0; off >>= 1) {
            #pragma unroll
            for (int r = 0; r < 4; ++r)
                pm[r] = fmaxf(pm[r], __shfl_xor(pm[r], off));
        }
        float pr[4][4], rs[4], sc[4];
        #pragma unroll
        for (int r = 0; r < 4; ++r) {
            float mn = fmaxf(m_r[r], pm[r]);
            sc[r]  = __expf(m_r[r] - mn);
            m_r[r] = mn;
            rs[r] = 0.f;
            #pragma unroll
            for (int h = 0; h < 4; ++h) {
                pr[h][r] = __expf(s[h][r] - mn);
                rs[r] += pr[h][r];
            }
        }
        #pragma unroll
        for (int off = 8; off > 0; off >>= 1) {
            #pragma unroll
            for (int r = 0; r < 4; ++r)
                rs[r] += __shfl_xor(rs[r], off);
        }
        #pragma unroll
        for (int r = 0; r < 4; ++r) l_r[r] = l_r[r] * sc[r] + rs[r];
        #pragma unroll
        for (int dc = 0; dc < 8; ++dc) {
            #pragma unroll
            for (int r = 0; r < 4; ++r) accO[dc][r] *= sc[r];
        }

        // ---- P -> bf16 -> per-wave LDS transpose (C-layout -> A-frag)
        unsigned short* pw = ptb[wid];
        #pragma unroll
        for (int h = 0; h < 4; ++h)
            #pragma unroll
            for (int r = 0; r < 4; ++r)
                pw[(lgrp * 4 + r) * 72 + h * 16 + lrow] = f2bf(pr[h][r]);
        asm volatile("s_waitcnt lgkmcnt(0)" ::: "memory");
        bf16x8 ap0 = __builtin_bit_cast(bf16x8, *(const us8*)&pw[lrow * 72 + lgrp * 8]);
        bf16x8 ap1 = __builtin_bit_cast(bf16x8, *(const us8*)&pw[lrow * 72 + 32 + lgrp * 8]);

        // ---- PV from LDS: O[16q x 128d] += P(16x64) . V(64x128)
        #pragma unroll
        for (int dc = 0; dc < 8; ++dc) {
            bf16x8 bv0 = __builtin_bit_cast(bf16x8,
                *(const us8*)&vl2[(dc * 2) * 512 + lane * 8]);
            accO[dc] = __builtin_amdgcn_mfma_f32_16x16x32_bf16(ap0, bv0, accO[dc], 0, 0, 0);
            bf16x8 bv1 = __builtin_bit_cast(bf16x8,
                *(const us8*)&vl2[(dc * 2 + 1) * 512 + lane * 8]);
            accO[dc] = __builtin_amdgcn_mfma_f32_16x16x32_bf16(ap1, bv1, accO[dc], 0, 0, 0);
        }

        // barrier: implicit vmcnt(0)+lgkmcnt(0) drains my stage issues (issued
        // a full tile of compute ago) and fences buffer reuse
        __syncthreads();
    }

    // ---- epilogue
    float inv[4];
    #pragma unroll
    for (int r = 0; r < 4; ++r) inv[r] = 1.0f / l_r[r];
    float* op = og + (size_t)(b * NQ + q0 + wid * 16) * ND;
    #pragma unroll
    for (int dc = 0; dc < 8; ++dc) {
        #pragma unroll
        for (int r = 0; r < 4; ++r)
            op[(lgrp * 4 + r) * ND + dc * 16 + lrow] = accO[dc][r] * inv[r];
    }
}

// ---------------------------------------------------------------------------
// Fallback (R1 kernel): used only if ws_size < 16 MB
// ---------------------------------------------------------------------------
__global__ __launch_bounds__(256, 2)
void attn_fused(const float* __restrict__ qg, const float* __restrict__ kg,
                const float* __restrict__ vg, const int* __restrict__ vlen,
                float* __restrict__ og)
{
    const int b    = blockIdx.y;
    const int q0   = blockIdx.x * QBLK;
    const int tid  = threadIdx.x;
    const int wid  = tid >> 6;
    const int lane = tid & 63;
    const int lrow = lane & 15;
    const int lgrp = lane >> 4;

    const int L = vlen[b];
    const bool uniform = (L <= 0);
    const int Leff = uniform ? NK : L;
    const int nt32 = (Leff + 31) / 32;

    __shared__ __align__(16) unsigned short kt[32 * 136];
    __shared__ __align__(16) unsigned short vt[128 * 40];
    __shared__ __align__(16) float pt[4][16 * 36];

    bf16x8 aq[4];
    {
        const float* qp = qg + (size_t)(b * NQ + q0 + wid * 16 + lrow) * ND + lgrp * 8;
        #pragma unroll
        for (int c = 0; c < 4; ++c) {
            f4 f0 = *(const f4*)(qp + c * 32);
            f4 f1 = *(const f4*)(qp + c * 32 + 4);
            us8 u;
            #pragma unroll
            for (int i = 0; i < 4; ++i) {
                u[i]     = f2bf(f0[i] * SCALE);
                u[i + 4] = f2bf(f1[i] * SCALE);
            }
            aq[c] = __builtin_bit_cast(bf16x8, u);
        }
    }

    float m_r[4], l_r[4];
    f4 accO[8];
    #pragma unroll
    for (int r = 0; r < 4; ++r) { m_r[r] = -__builtin_inff(); l_r[r] = 0.f; }
    #pragma unroll
    for (int dc = 0; dc < 8; ++dc) accO[dc] = splat4(0.f);

    for (int t = 0; t < nt32; ++t) {
        const int kv0 = t * 32;
        __syncthreads();
        {
            const int r  = tid >> 3;
            const int c0 = (tid & 7) * 16;
            const float* gp = kg + (size_t)(b * NK + kv0 + r) * ND + c0;
            f4 f0 = *(const f4*)(gp);
            f4 f1 = *(const f4*)(gp + 4);
            f4 f2 = *(const f4*)(gp + 8);
            f4 f3 = *(const f4*)(gp + 12);
            us8 w0, w1;
            #pragma unroll
            for (int i = 0; i < 4; ++i) {
                w0[i]     = f2bf(f0[i]);
                w0[i + 4] = f2bf(f1[i]);
                w1[i]     = f2bf(f2[i]);
                w1[i + 4] = f2bf(f3[i]);
            }
            unsigned short* dst = &kt[r * 136 + c0];
            *(us8*)(dst)     = w0;
            *(us8*)(dst + 8) = w1;
        }
        {
            const int d  = tid & 127;
            const int g2 = tid >> 7;
            const float* gp = vg + (size_t)(b * NK + kv0 + g2 * 16) * ND + d;
            us8 w0, w1;
            #pragma unroll
            for (int j = 0; j < 8; ++j) {
                w0[j] = f2bf(gp[(size_t)j * ND]);
                w1[j] = f2bf(gp[(size_t)(j + 8) * ND]);
            }
            unsigned short* dst = &vt[d * 40 + g2 * 16];
            *(us8*)(dst)     = w0;
            *(us8*)(dst + 8) = w1;
        }
        __syncthreads();

        f4 s0 = splat4(0.f), s1 = splat4(0.f);
        #pragma unroll
        for (int c = 0; c < 4; ++c) {
            bf16x8 bk0 = __builtin_bit_cast(bf16x8,
                *(const us8*)&kt[lrow * 136 + c * 32 + lgrp * 8]);
            s0 = __builtin_amdgcn_mfma_f32_16x16x32_bf16(aq[c], bk0, s0, 0, 0, 0);
            bf16x8 bk1 = __builtin_bit_cast(bf16x8,
                *(const us8*)&kt[(16 + lrow) * 136 + c * 32 + lgrp * 8]);
            s1 = __builtin_amdgcn_mfma_f32_16x16x32_bf16(aq[c], bk1, s1, 0, 0, 0);
        }

        const int col0 = kv0 + lrow;
        if (uniform) {
            s0 = splat4(0.f);
            s1 = splat4(0.f);
        } else {
            if (col0 >= L)      s0 = splat4(-__builtin_inff());
            if (col0 + 16 >= L) s1 = splat4(-__builtin_inff());
        }

        float pm[4];
        #pragma unroll
        for (int r = 0; r < 4; ++r) pm[r] = fmaxf(s0[r], s1[r]);
        #pragma unroll
        for (int off = 8; off > 0; off >>= 1) {
            #pragma unroll
            for (int r = 0; r < 4; ++r)
                pm[r] = fmaxf(pm[r], __shfl_xor(pm[r], off));
        }
        float pr0[4], pr1[4], rs[4], sc[4];
        #pragma unroll
        for (int r = 0; r < 4; ++r) {
            float mn = fmaxf(m_r[r], pm[r]);
            sc[r]  = __expf(m_r[r] - mn);
            m_r[r] = mn;
            pr0[r] = __expf(s0[r] - mn);
            pr1[r] = __expf(s1[r] - mn);
            rs[r]  = pr0[r] + pr1[r];
        }
        #pragma unroll
        for (int off = 8; off > 0; off >>= 1) {
            #pragma unroll
            for (int r = 0; r < 4; ++r)
                rs[r] += __shfl_xor(rs[r], off);
        }
        #pragma unroll
        for (int r = 0; r < 4; ++r) l_r[r] = l_r[r] * sc[r] + rs[r];
        #pragma unroll
        for (int dc = 0; dc < 8; ++dc) {
            #pragma unroll
            for (int r = 0; r < 4; ++r) accO[dc][r] *= sc[r];
        }

        float* pw = pt[wid];
        #pragma unroll
        for (int r = 0; r < 4; ++r) {
            pw[(lgrp * 4 + r) * 36 + lrow]      = pr0[r];
            pw[(lgrp * 4 + r) * 36 + 16 + lrow] = pr1[r];
        }
        asm volatile("s_waitcnt lgkmcnt(0)" ::: "memory");
        f4 a0 = *(const f4*)&pw[lrow * 36 + lgrp * 8];
        f4 a1 = *(const f4*)&pw[lrow * 36 + lgrp * 8 + 4];
        us8 au;
        #pragma unroll
        for (int i = 0; i < 4; ++i) { au[i] = f2bf(a0[i]); au[i + 4] = f2bf(a1[i]); }
        bf16x8 ap = __builtin_bit_cast(bf16x8, au);

        #pragma unroll
        for (int dc = 0; dc < 8; ++dc) {
            bf16x8 bv = __builtin_bit_cast(bf16x8,
                *(const us8*)&vt[(dc * 16 + lrow) * 40 + lgrp * 8]);
            accO[dc] = __builtin_amdgcn_mfma_f32_16x16x32_bf16(ap, bv, accO[dc], 0, 0, 0);
        }
    }

    float inv[4];
    #pragma unroll
    for (int r = 0; r < 4; ++r) inv[r] = 1.0f / l_r[r];
    float* op = og + (size_t)(b * NQ + q0 + wid * 16) * ND;
    #pragma unroll
    for (int dc = 0; dc < 8; ++dc) {
        #pragma unroll
        for (int r = 0; r < 4; ++r)
            op[(lgrp * 4 + r) * ND + dc * 16 + lrow] = accO[dc][r] * inv[r];
    }
}

extern "C" void kernel_launch(void* const* d_in, const int* in_sizes, int n_in,
                              void* d_out, int out_size, void* d_ws, size_t ws_size,
                              hipStream_t stream) {
    (void)in_sizes; (void)n_in; (void)out_size;
    const float* q  = (const float*)d_in[0];
    const float* k  = (const float*)d_in[1];
    const float* v  = (const float*)d_in[2];
    const int*   vl = (const int*)d_in[3];
    float* out = (float*)d_out;

    const size_t half = (size_t)NB * NK * ND * sizeof(unsigned short); // 8 MB
    if (ws_size >= 2 * half) {
        unsigned short* wk  = (unsigned short*)d_ws;
        unsigned short* wvt = wk + (size_t)NB * NK * ND;
        hipLaunchKernelGGL(prep_kv3, dim3(NTILE, NB), dim3(256), 0, stream, k, v, wk, wvt);
        hipLaunchKernelGGL(attn_fused4, dim3(NQ / QBLK * NB), dim3(256), 0, stream,
                           q, vl, wk, wvt, out);
    } else {
        hipLaunchKernelGGL(attn_fused, dim3(NQ / QBLK, NB), dim3(256), 0, stream,
                           q, k, v, vl, out);
    }
}

// Round 5
// 84.372 us; speedup vs baseline: 2.5573x; 1.0097x over previous
//
#include <hip/hip_runtime.h>

// Problem constants (reference: B=16, Q=2048, K=2048, D=128, fp32, NEG=-1e6)
constexpr int NB = 16;
constexpr int NQ = 2048;
constexpr int NK = 2048;
constexpr int ND = 128;
constexpr int KVBLK = 64;                 // kv per tile
constexpr int NTILE = NK / KVBLK;         // 32
constexpr int TILE_USH = KVBLK * ND;      // 8192 ushorts = 16KB per tile
constexpr float SCALE = 0.08838834764831844f; // 1/sqrt(128)

typedef __attribute__((ext_vector_type(4))) float f4;
typedef __attribute__((ext_vector_type(16))) float f32x16;
typedef __attribute__((ext_vector_type(8))) unsigned short us8;
typedef __attribute__((ext_vector_type(8))) __bf16 bf16x8;
typedef __attribute__((ext_vector_type(4))) unsigned int u32x4;

static __device__ __forceinline__ unsigned short f2bf(float f) {
    unsigned u = __builtin_bit_cast(unsigned, f);
    u += 0x7fffu + ((u >> 16) & 1u);
    return (unsigned short)(u >> 16);
}
static __device__ __forceinline__ f4 splat4(float x) { f4 r = {x,x,x,x}; return r; }

static __device__ __forceinline__ void load_lds16(const unsigned short* g, unsigned short* l) {
    __builtin_amdgcn_global_load_lds(
        (const __attribute__((address_space(1))) void*)g,
        (__attribute__((address_space(3))) void*)l,
        16, 0, 0);
}

static __device__ __forceinline__ unsigned cvt_pk_bf16(float lo, float hi) {
    unsigned r;
    asm("v_cvt_pk_bf16_f32 %0, %1, %2" : "=v"(r) : "v"(lo), "v"(hi));
    return r;
}

// ---------------------------------------------------------------------------
// Prep: per (batch, kv-tile=64) write K and V in lane-linear 32x32-MFMA
// fragment order:
//  K  (kv,d): off = ((kv>>5)*8 + (d>>4))*512 + ((d>>3)&1)*256 + (kv&31)*8 + (d&7)
//  V  (kv,d): off = ((kv>>4)*4 + (d>>5))*512 + ((kv>>3)&1)*256 + (d&31)*8 + (kv&7)
// grid (NTILE, NB), 256 threads
// ---------------------------------------------------------------------------
__global__ __launch_bounds__(256)
void prep_kv4(const float* __restrict__ kg, const float* __restrict__ vg,
              unsigned short* __restrict__ wk, unsigned short* __restrict__ wvt)
{
    const int b   = blockIdx.y;
    const int t   = blockIdx.x;
    const int kv0 = t * KVBLK;
    const int t0  = threadIdx.x;

    __shared__ __align__(16) unsigned short vl[64 * 136];

    // ---- K: coalesced read, fragment-lane-linear 16B writes
    {
        const int kv = t0 >> 2;
        const int c  = t0 & 3;
        const float* gp = kg + (size_t)(b * NK + kv0 + kv) * ND + c * 32;
        unsigned short* ob = wk + (size_t)(b * NTILE + t) * TILE_USH;
        #pragma unroll
        for (int g = 0; g < 4; ++g) {
            f4 f0 = *(const f4*)(gp + g * 8);
            f4 f1 = *(const f4*)(gp + g * 8 + 4);
            us8 w;
            #pragma unroll
            for (int i = 0; i < 4; ++i) { w[i] = f2bf(f0[i]); w[i+4] = f2bf(f1[i]); }
            const int d0 = c * 32 + g * 8;
            const int f  = (kv >> 5) * 8 + (d0 >> 4);
            const int off = f * 512 + ((d0 >> 3) & 1) * 256 + (kv & 31) * 8;
            *(us8*)(ob + off) = w;
        }
    }
    // ---- V: coalesced read -> LDS [64 kv][136 d]
    {
        const int kv = t0 >> 2;
        const int d0 = (t0 & 3) * 32;
        const float* gp = vg + (size_t)(b * NK + kv0 + kv) * ND + d0;
        unsigned short* lb = &vl[kv * 136 + d0];
        #pragma unroll
        for (int g = 0; g < 4; ++g) {
            f4 f0 = *(const f4*)(gp + g * 8);
            f4 f1 = *(const f4*)(gp + g * 8 + 4);
            us8 w;
            #pragma unroll
            for (int i = 0; i < 4; ++i) { w[i] = f2bf(f0[i]); w[i+4] = f2bf(f1[i]); }
            *(us8*)(lb + g * 8) = w;
        }
    }
    __syncthreads();
    // ---- V out: lane-linear 16B chunks, coalesced
    {
        unsigned short* ob = wvt + (size_t)(b * NTILE + t) * TILE_USH;
        #pragma unroll
        for (int iter = 0; iter < 4; ++iter) {
            const int cid = iter * 256 + t0;      // chunk id = f*64 + lane
            const int f   = cid >> 6;
            const int l   = cid & 63;
            const int kb  = (f >> 2) * 16 + (l >> 5) * 8;
            const int d   = (f & 3) * 32 + (l & 31);
            us8 w;
            #pragma unroll
            for (int j = 0; j < 8; ++j) w[j] = vl[(kb + j) * 136 + d];
            *(us8*)(ob + cid * 8) = w;
        }
    }
}

// ---------------------------------------------------------------------------
// Fused attention v5: 4 waves x 32 q-rows, 32x32x16 MFMA, swapped QK^T,
// fully in-register softmax (1 shfl combine), LDS double-buffered K/V via
// global_load_lds. No per-tile cross-lane trees, no P LDS round-trip.
// ---------------------------------------------------------------------------
__global__ __launch_bounds__(256, 1)
void attn_fused5(const float* __restrict__ qg, const int* __restrict__ vlen,
                 const unsigned short* __restrict__ wk,
                 const unsigned short* __restrict__ wvt,
                 float* __restrict__ og)
{
    const int bid = blockIdx.x;
    const int b   = bid & 15;      // XCD x hosts batches {x, x+8}: KV L2-resident
    const int qc  = bid >> 4;
    const int q0  = qc * 128;

    const int tid  = threadIdx.x;
    const int wid  = tid >> 6;
    const int lane = tid & 63;
    const int lq   = lane & 31;    // this lane's q-row (and its d-col in O)
    const int hi   = lane >> 5;

    const int L = vlen[b];
    const bool uniform = (L <= 0);
    const int Leff = uniform ? NK : L;
    const int ntiles = (Leff + KVBLK - 1) / KVBLK;

    __shared__ __align__(16) unsigned short kvbuf[2][2 * TILE_USH];

    // ---- Q fragments (B-operand): lane holds Q[q0+wid*32+lq][c*16+hi*8+j], scaled
    bf16x8 aq[8];
    {
        const float* qp = qg + (size_t)(b * NQ + q0 + wid * 32 + lq) * ND + hi * 8;
        #pragma unroll
        for (int c = 0; c < 8; ++c) {
            f4 f0 = *(const f4*)(qp + c * 16);
            f4 f1 = *(const f4*)(qp + c * 16 + 4);
            us8 u;
            #pragma unroll
            for (int i = 0; i < 4; ++i) {
                u[i]     = f2bf(f0[i] * SCALE);
                u[i + 4] = f2bf(f1[i] * SCALE);
            }
            aq[c] = __builtin_bit_cast(bf16x8, u);
        }
    }

    const unsigned short* kb = wk  + (size_t)b * NTILE * TILE_USH;
    const unsigned short* vb = wvt + (size_t)b * NTILE * TILE_USH;

    const int s_half = wid >> 1;
    const int s_sub  = wid & 1;
    const int s_off  = s_sub * 4096 + lane * 8;

    float m_r = -__builtin_inff();
    float l_r = 0.f;
    f32x16 accO[4];
    #pragma unroll
    for (int dc = 0; dc < 4; ++dc)
        #pragma unroll
        for (int r = 0; r < 16; ++r) accO[dc][r] = 0.f;

    // row constants of the 32x32 C layout: row = (r&3) + 8*(r>>2) (+4*hi)
    // (compile-time per r)

    // ---- prologue: stage tile 0
    {
        const unsigned short* src = (s_half ? vb : kb) + s_off;
        unsigned short* dst = &kvbuf[0][s_half * 8192 + s_sub * 4096];
        #pragma unroll
        for (int j = 0; j < 8; ++j) load_lds16(src + j * 512, dst + j * 512);
    }
    __syncthreads();

    for (int t = 0; t < ntiles; ++t) {
        const int kv0 = t * KVBLK;
        const int cur = t & 1;
        const unsigned short* kl = &kvbuf[cur][0];
        const unsigned short* vl2 = &kvbuf[cur][8192];

        // ---- issue stage(t+1)
        if (t + 1 < ntiles) {
            const unsigned short* src =
                (s_half ? vb : kb) + (size_t)(t + 1) * TILE_USH + s_off;
            unsigned short* dst = &kvbuf[cur ^ 1][s_half * 8192 + s_sub * 4096];
            #pragma unroll
            for (int j = 0; j < 8; ++j) load_lds16(src + j * 512, dst + j * 512);
        }

        // ---- swapped QK^T: S^T[64k x 32q], A=K frags (LDS), B=Q regs
        f32x16 sA, sB;
        #pragma unroll
        for (int r = 0; r < 16; ++r) { sA[r] = 0.f; sB[r] = 0.f; }
        #pragma unroll
        for (int c = 0; c < 8; ++c) {
            bf16x8 k0 = __builtin_bit_cast(bf16x8, *(const us8*)&kl[c * 512 + lane * 8]);
            sA = __builtin_amdgcn_mfma_f32_32x32x16_bf16(k0, aq[c], sA, 0, 0, 0);
        }
        #pragma unroll
        for (int c = 0; c < 8; ++c) {
            bf16x8 k1 = __builtin_bit_cast(bf16x8, *(const us8*)&kl[(8 + c) * 512 + lane * 8]);
            sB = __builtin_amdgcn_mfma_f32_32x32x16_bf16(k1, aq[c], sB, 0, 0, 0);
        }

        // ---- mask (rows = k)
        if (uniform) {
            #pragma unroll
            for (int r = 0; r < 16; ++r) { sA[r] = 0.f; sB[r] = 0.f; }
        } else {
            const int lim0 = L - kv0 - 4 * hi;       // kt2=0: masked iff rc >= lim0
            const int lim1 = lim0 - 32;              // kt2=1
            #pragma unroll
            for (int r = 0; r < 16; ++r) {
                const int rc = (r & 3) + 8 * (r >> 2);
                sA[r] = (rc >= lim0) ? -__builtin_inff() : sA[r];
                sB[r] = (rc >= lim1) ? -__builtin_inff() : sB[r];
            }
        }

        // ---- in-register softmax for q = lq (lane-local; partner lane has other k-half)
        float mx[8];
        #pragma unroll
        for (int i = 0; i < 8; ++i)
            mx[i] = fmaxf(fmaxf(sA[i], sA[i + 8]), fmaxf(sB[i], sB[i + 8]));
        #pragma unroll
        for (int i = 0; i < 4; ++i) mx[i] = fmaxf(mx[i], mx[i + 4]);
        float pm = fmaxf(fmaxf(mx[0], mx[1]), fmaxf(mx[2], mx[3]));
        float pmax = fmaxf(pm, __shfl_xor(pm, 32));

        // T13: rescale only when some q-row got a new max
        if (__any(pmax > m_r)) {
            const float mnew = fmaxf(m_r, pmax);
            const float sc = __expf(m_r - mnew);
            m_r = mnew;
            l_r *= sc;
            #pragma unroll
            for (int r = 0; r < 16; ++r) {
                const int src = ((r & 3) + 8 * (r >> 2) + 4 * hi) + (lane & 32);
                const float scr = __shfl(sc, src);
                accO[0][r] *= scr; accO[1][r] *= scr;
                accO[2][r] *= scr; accO[3][r] *= scr;
            }
        }

        // ---- exp + row-sum
        float p0[16], p1[16];
        #pragma unroll
        for (int r = 0; r < 16; ++r) {
            p0[r] = __expf(sA[r] - m_r);
            p1[r] = __expf(sB[r] - m_r);
        }
        float sm[8];
        #pragma unroll
        for (int i = 0; i < 8; ++i)
            sm[i] = (p0[i] + p0[i + 8]) + (p1[i] + p1[i + 8]);
        #pragma unroll
        for (int i = 0; i < 4; ++i) sm[i] += sm[i + 4];
        float rs = (sm[0] + sm[1]) + (sm[2] + sm[3]);
        rs += __shfl_xor(rs, 32);
        l_r += rs;

        // ---- P -> bf16 packed words; half-exchange to build PV A-frags
        unsigned cw[16];
        #pragma unroll
        for (int i = 0; i < 8; ++i) cw[i] = cvt_pk_bf16(p0[2 * i], p0[2 * i + 1]);
        #pragma unroll
        for (int i = 0; i < 8; ++i) cw[8 + i] = cvt_pk_bf16(p1[2 * i], p1[2 * i + 1]);

        bf16x8 pa[4];
        #pragma unroll
        for (int ks = 0; ks < 4; ++ks) {
            const int a = 4 * ks;
            const unsigned u = hi ? cw[a]     : cw[a + 2];
            const unsigned v = hi ? cw[a + 1] : cw[a + 3];
            const unsigned up = __shfl_xor((int)u, 32);
            const unsigned vp = __shfl_xor((int)v, 32);
            u32x4 w;
            w[0] = hi ? up        : cw[a];
            w[1] = hi ? vp        : cw[a + 1];
            w[2] = hi ? cw[a + 2] : up;
            w[3] = hi ? cw[a + 3] : vp;
            pa[ks] = __builtin_bit_cast(bf16x8, w);
        }

        // ---- PV: O[32q x 128d] += P(32x64) . V(64x128), B=V frags (LDS)
        #pragma unroll
        for (int dc = 0; dc < 4; ++dc) {
            #pragma unroll
            for (int ks = 0; ks < 4; ++ks) {
                bf16x8 bv = __builtin_bit_cast(bf16x8,
                    *(const us8*)&vl2[(ks * 4 + dc) * 512 + lane * 8]);
                accO[dc] = __builtin_amdgcn_mfma_f32_32x32x16_bf16(pa[ks], bv, accO[dc], 0, 0, 0);
            }
        }

        __syncthreads();   // drains stage issues (vmcnt 0) + fences buffer reuse
    }

    // ---- epilogue: redistribute 1/l to C rows, store
    const float inv = 1.0f / l_r;
    float* ob = og + (size_t)(b * NQ + q0 + wid * 32) * ND;
    #pragma unroll
    for (int r = 0; r < 16; ++r) {
        const int row = (r & 3) + 8 * (r >> 2) + 4 * hi;
        const float invr = __shfl(inv, row + (lane & 32));
        #pragma unroll
        for (int dc = 0; dc < 4; ++dc)
            ob[(size_t)row * ND + dc * 32 + lq] = accO[dc][r] * invr;
    }
}

// ---------------------------------------------------------------------------
// Fallback (R1 kernel): used only if ws_size < 16 MB
// ---------------------------------------------------------------------------
__global__ __launch_bounds__(256, 2)
void attn_fused(const float* __restrict__ qg, const float* __restrict__ kg,
                const float* __restrict__ vg, const int* __restrict__ vlen,
                float* __restrict__ og)
{
    const int b    = blockIdx.y;
    const int q0   = blockIdx.x * 64;
    const int tid  = threadIdx.x;
    const int wid  = tid >> 6;
    const int lane = tid & 63;
    const int lrow = lane & 15;
    const int lgrp = lane >> 4;

    const int L = vlen[b];
    const bool uniform = (L <= 0);
    const int Leff = uniform ? NK : L;
    const int nt32 = (Leff + 31) / 32;

    __shared__ __align__(16) unsigned short kt[32 * 136];
    __shared__ __align__(16) unsigned short vt[128 * 40];
    __shared__ __align__(16) float pt[4][16 * 36];

    bf16x8 aqf[4];
    {
        const float* qp = qg + (size_t)(b * NQ + q0 + wid * 16 + lrow) * ND + lgrp * 8;
        #pragma unroll
        for (int c = 0; c < 4; ++c) {
            f4 f0 = *(const f4*)(qp + c * 32);
            f4 f1 = *(const f4*)(qp + c * 32 + 4);
            us8 u;
            #pragma unroll
            for (int i = 0; i < 4; ++i) {
                u[i]     = f2bf(f0[i] * SCALE);
                u[i + 4] = f2bf(f1[i] * SCALE);
            }
            aqf[c] = __builtin_bit_cast(bf16x8, u);
        }
    }

    float m_r[4], l_r[4];
    f4 accO[8];
    #pragma unroll
    for (int r = 0; r < 4; ++r) { m_r[r] = -__builtin_inff(); l_r[r] = 0.f; }
    #pragma unroll
    for (int dc = 0; dc < 8; ++dc) accO[dc] = splat4(0.f);

    for (int t = 0; t < nt32; ++t) {
        const int kv0 = t * 32;
        __syncthreads();
        {
            const int r  = tid >> 3;
            const int c0 = (tid & 7) * 16;
            const float* gp = kg + (size_t)(b * NK + kv0 + r) * ND + c0;
            f4 f0 = *(const f4*)(gp);
            f4 f1 = *(const f4*)(gp + 4);
            f4 f2 = *(const f4*)(gp + 8);
            f4 f3 = *(const f4*)(gp + 12);
            us8 w0, w1;
            #pragma unroll
            for (int i = 0; i < 4; ++i) {
                w0[i]     = f2bf(f0[i]);
                w0[i + 4] = f2bf(f1[i]);
                w1[i]     = f2bf(f2[i]);
                w1[i + 4] = f2bf(f3[i]);
            }
            unsigned short* dst = &kt[r * 136 + c0];
            *(us8*)(dst)     = w0;
            *(us8*)(dst + 8) = w1;
        }
        {
            const int d  = tid & 127;
            const int g2 = tid >> 7;
            const float* gp = vg + (size_t)(b * NK + kv0 + g2 * 16) * ND + d;
            us8 w0, w1;
            #pragma unroll
            for (int j = 0; j < 8; ++j) {
                w0[j] = f2bf(gp[(size_t)j * ND]);
                w1[j] = f2bf(gp[(size_t)(j + 8) * ND]);
            }
            unsigned short* dst = &vt[d * 40 + g2 * 16];
            *(us8*)(dst)     = w0;
            *(us8*)(dst + 8) = w1;
        }
        __syncthreads();

        f4 s0 = splat4(0.f), s1 = splat4(0.f);
        #pragma unroll
        for (int c = 0; c < 4; ++c) {
            bf16x8 bk0 = __builtin_bit_cast(bf16x8,
                *(const us8*)&kt[lrow * 136 + c * 32 + lgrp * 8]);
            s0 = __builtin_amdgcn_mfma_f32_16x16x32_bf16(aqf[c], bk0, s0, 0, 0, 0);
            bf16x8 bk1 = __builtin_bit_cast(bf16x8,
                *(const us8*)&kt[(16 + lrow) * 136 + c * 32 + lgrp * 8]);
            s1 = __builtin_amdgcn_mfma_f32_16x16x32_bf16(aqf[c], bk1, s1, 0, 0, 0);
        }

        const int col0 = kv0 + lrow;
        if (uniform) {
            s0 = splat4(0.f);
            s1 = splat4(0.f);
        } else {
            if (col0 >= L)      s0 = splat4(-__builtin_inff());
            if (col0 + 16 >= L) s1 = splat4(-__builtin_inff());
        }

        float pm[4];
        #pragma unroll
        for (int r = 0; r < 4; ++r) pm[r] = fmaxf(s0[r], s1[r]);
        #pragma unroll
        for (int off = 8; off > 0; off >>= 1) {
            #pragma unroll
            for (int r = 0; r < 4; ++r)
                pm[r] = fmaxf(pm[r], __shfl_xor(pm[r], off));
        }
        float pr0[4], pr1[4], rs[4], sc[4];
        #pragma unroll
        for (int r = 0; r < 4; ++r) {
            float mn = fmaxf(m_r[r], pm[r]);
            sc[r]  = __expf(m_r[r] - mn);
            m_r[r] = mn;
            pr0[r] = __expf(s0[r] - mn);
            pr1[r] = __expf(s1[r] - mn);
            rs[r]  = pr0[r] + pr1[r];
        }
        #pragma unroll
        for (int off = 8; off > 0; off >>= 1) {
            #pragma unroll
            for (int r = 0; r < 4; ++r)
                rs[r] += __shfl_xor(rs[r], off);
        }
        #pragma unroll
        for (int r = 0; r < 4; ++r) l_r[r] = l_r[r] * sc[r] + rs[r];
        #pragma unroll
        for (int dc = 0; dc < 8; ++dc) {
            #pragma unroll
            for (int r = 0; r < 4; ++r) accO[dc][r] *= sc[r];
        }

        float* pw = pt[wid];
        #pragma unroll
        for (int r = 0; r < 4; ++r) {
            pw[(lgrp * 4 + r) * 36 + lrow]      = pr0[r];
            pw[(lgrp * 4 + r) * 36 + 16 + lrow] = pr1[r];
        }
        asm volatile("s_waitcnt lgkmcnt(0)" ::: "memory");
        f4 a0 = *(const f4*)&pw[lrow * 36 + lgrp * 8];
        f4 a1 = *(const f4*)&pw[lrow * 36 + lgrp * 8 + 4];
        us8 au;
        #pragma unroll
        for (int i = 0; i < 4; ++i) { au[i] = f2bf(a0[i]); au[i + 4] = f2bf(a1[i]); }
        bf16x8 ap = __builtin_bit_cast(bf16x8, au);

        #pragma unroll
        for (int dc = 0; dc < 8; ++dc) {
            bf16x8 bv = __builtin_bit_cast(bf16x8,
                *(const us8*)&vt[(dc * 16 + lrow) * 40 + lgrp * 8]);
            accO[dc] = __builtin_amdgcn_mfma_f32_16x16x32_bf16(ap, bv, accO[dc], 0, 0, 0);
        }
    }

    float inv[4];
    #pragma unroll
    for (int r = 0; r < 4; ++r) inv[r] = 1.0f / l_r[r];
    float* op = og + (size_t)(b * NQ + q0 + wid * 16) * ND;
    #pragma unroll
    for (int dc = 0; dc < 8; ++dc) {
        #pragma unroll
        for (int r = 0; r < 4; ++r)
            op[(lgrp * 4 + r) * ND + dc * 16 + lrow] = accO[dc][r] * inv[r];
    }
}

extern "C" void kernel_launch(void* const* d_in, const int* in_sizes, int n_in,
                              void* d_out, int out_size, void* d_ws, size_t ws_size,
                              hipStream_t stream) {
    (void)in_sizes; (void)n_in; (void)out_size;
    const float* q  = (const float*)d_in[0];
    const float* k  = (const float*)d_in[1];
    const float* v  = (const float*)d_in[2];
    const int*   vl = (const int*)d_in[3];
    float* out = (float*)d_out;

    const size_t half = (size_t)NB * NK * ND * sizeof(unsigned short); // 8 MB
    if (ws_size >= 2 * half) {
        unsigned short* wk  = (unsigned short*)d_ws;
        unsigned short* wvt = wk + (size_t)NB * NK * ND;
        hipLaunchKernelGGL(prep_kv4, dim3(NTILE, NB), dim3(256), 0, stream, k, v, wk, wvt);
        hipLaunchKernelGGL(attn_fused5, dim3((NQ / 128) * NB), dim3(256), 0, stream,
                           q, vl, wk, wvt, out);
    } else {
        hipLaunchKernelGGL(attn_fused, dim3(NQ / 64, NB), dim3(256), 0, stream,
                           q, k, v, vl, out);
    }
}

// Round 6
// 65.992 us; speedup vs baseline: 3.2696x; 1.2785x over previous
//
#include <hip/hip_runtime.h>

// Problem constants (reference: B=16, Q=2048, K=2048, D=128, fp32, NEG=-1e6)
constexpr int NB = 16;
constexpr int NQ = 2048;
constexpr int NK = 2048;
constexpr int ND = 128;
constexpr int KVBLK = 64;                 // kv per tile
constexpr int NTILE = NK / KVBLK;         // 32
constexpr int TILE_USH = KVBLK * ND;      // 8192 ushorts = 16KB per tile
constexpr float SCALE = 0.08838834764831844f; // 1/sqrt(128)

typedef __attribute__((ext_vector_type(4))) float f4;
typedef __attribute__((ext_vector_type(16))) float f32x16;
typedef __attribute__((ext_vector_type(8))) unsigned short us8;
typedef __attribute__((ext_vector_type(8))) __bf16 bf16x8;
typedef __attribute__((ext_vector_type(4))) unsigned int u32x4;

static __device__ __forceinline__ unsigned short f2bf(float f) {
    unsigned u = __builtin_bit_cast(unsigned, f);
    u += 0x7fffu + ((u >> 16) & 1u);
    return (unsigned short)(u >> 16);
}
static __device__ __forceinline__ f4 splat4(float x) { f4 r = {x,x,x,x}; return r; }

static __device__ __forceinline__ void load_lds16(const unsigned short* g, unsigned short* l) {
    __builtin_amdgcn_global_load_lds(
        (const __attribute__((address_space(1))) void*)g,
        (__attribute__((address_space(3))) void*)l,
        16, 0, 0);
}

static __device__ __forceinline__ unsigned cvt_pk_bf16(float lo, float hi) {
    unsigned r;
    asm("v_cvt_pk_bf16_f32 %0, %1, %2" : "=v"(r) : "v"(lo), "v"(hi));
    return r;
}

// ---------------------------------------------------------------------------
// Prep: per (batch, kv-tile=64) write K and V in lane-linear 32x32-MFMA
// fragment order:
//  K  (kv,d): off = ((kv>>5)*8 + (d>>4))*512 + ((d>>3)&1)*256 + (kv&31)*8 + (d&7)
//  V  (kv,d): off = ((kv>>4)*4 + (d>>5))*512 + ((kv>>3)&1)*256 + (d&31)*8 + (kv&7)
// grid (NTILE, NB), 256 threads
// ---------------------------------------------------------------------------
__global__ __launch_bounds__(256)
void prep_kv4(const float* __restrict__ kg, const float* __restrict__ vg,
              unsigned short* __restrict__ wk, unsigned short* __restrict__ wvt)
{
    const int b   = blockIdx.y;
    const int t   = blockIdx.x;
    const int kv0 = t * KVBLK;
    const int t0  = threadIdx.x;

    __shared__ __align__(16) unsigned short vl[64 * 136];

    // ---- K: coalesced read, fragment-lane-linear 16B writes
    {
        const int kv = t0 >> 2;
        const int c  = t0 & 3;
        const float* gp = kg + (size_t)(b * NK + kv0 + kv) * ND + c * 32;
        unsigned short* ob = wk + (size_t)(b * NTILE + t) * TILE_USH;
        #pragma unroll
        for (int g = 0; g < 4; ++g) {
            f4 f0 = *(const f4*)(gp + g * 8);
            f4 f1 = *(const f4*)(gp + g * 8 + 4);
            us8 w;
            #pragma unroll
            for (int i = 0; i < 4; ++i) { w[i] = f2bf(f0[i]); w[i+4] = f2bf(f1[i]); }
            const int d0 = c * 32 + g * 8;
            const int f  = (kv >> 5) * 8 + (d0 >> 4);
            const int off = f * 512 + ((d0 >> 3) & 1) * 256 + (kv & 31) * 8;
            *(us8*)(ob + off) = w;
        }
    }
    // ---- V: coalesced read -> LDS [64 kv][136 d]
    {
        const int kv = t0 >> 2;
        const int d0 = (t0 & 3) * 32;
        const float* gp = vg + (size_t)(b * NK + kv0 + kv) * ND + d0;
        unsigned short* lb = &vl[kv * 136 + d0];
        #pragma unroll
        for (int g = 0; g < 4; ++g) {
            f4 f0 = *(const f4*)(gp + g * 8);
            f4 f1 = *(const f4*)(gp + g * 8 + 4);
            us8 w;
            #pragma unroll
            for (int i = 0; i < 4; ++i) { w[i] = f2bf(f0[i]); w[i+4] = f2bf(f1[i]); }
            *(us8*)(lb + g * 8) = w;
        }
    }
    __syncthreads();
    // ---- V out: lane-linear 16B chunks, coalesced
    {
        unsigned short* ob = wvt + (size_t)(b * NTILE + t) * TILE_USH;
        #pragma unroll
        for (int iter = 0; iter < 4; ++iter) {
            const int cid = iter * 256 + t0;      // chunk id = f*64 + lane
            const int f   = cid >> 6;
            const int l   = cid & 63;
            const int kb  = (f >> 2) * 16 + (l >> 5) * 8;
            const int d   = (f & 3) * 32 + (l & 31);
            us8 w;
            #pragma unroll
            for (int j = 0; j < 8; ++j) w[j] = vl[(kb + j) * 136 + d];
            *(us8*)(ob + cid * 8) = w;
        }
    }
}

// ---------------------------------------------------------------------------
// Fused attention v6: 8 waves (512 thr), intra-block KV split into 2 groups
// of 4 waves (group g handles tiles t%2==g) -> 2 waves/SIMD with grid=256.
// Swapped 32x32x16 QK^T, in-register softmax, LDS dbuf staging per group,
// LDS merge epilogue.
// ---------------------------------------------------------------------------
__global__ __launch_bounds__(512, 2)
void attn_fused6(const float* __restrict__ qg, const int* __restrict__ vlen,
                 const unsigned short* __restrict__ wk,
                 const unsigned short* __restrict__ wvt,
                 float* __restrict__ og)
{
    const int bid = blockIdx.x;
    const int b   = bid & 15;      // XCD x hosts batches {x, x+8}: KV L2-resident
    const int qc  = bid >> 4;
    const int q0  = qc * 128;

    const int tid  = threadIdx.x;
    const int wid  = tid >> 6;
    const int grp  = wid >> 2;     // KV-split group 0/1
    const int w4   = wid & 3;      // q-chunk within block (32 rows each)
    const int lane = tid & 63;
    const int lq   = lane & 31;    // this lane's q-row (and d-col in O)
    const int hi   = lane >> 5;

    const int L = vlen[b];
    const bool uniform = (L <= 0);
    const int Leff = uniform ? NK : L;
    const int ntiles = (Leff + KVBLK - 1) / KVBLK;
    const int ng    = (ntiles + 1 - grp) >> 1;   // tiles this group owns
    const int niter = (ntiles + 1) >> 1;

    // [group][buf][K 16KB | V 16KB] = 128 KB; epilogue aliases this region
    __shared__ __align__(16) unsigned short smem[2][2][2 * TILE_USH];

    // ---- Q fragments (B-operand): lane holds Q[q0+w4*32+lq][c*16+hi*8+j], scaled
    bf16x8 aq[8];
    {
        const float* qp = qg + (size_t)(b * NQ + q0 + w4 * 32 + lq) * ND + hi * 8;
        #pragma unroll
        for (int c = 0; c < 8; ++c) {
            f4 f0 = *(const f4*)(qp + c * 16);
            f4 f1 = *(const f4*)(qp + c * 16 + 4);
            us8 u;
            #pragma unroll
            for (int i = 0; i < 4; ++i) {
                u[i]     = f2bf(f0[i] * SCALE);
                u[i + 4] = f2bf(f1[i] * SCALE);
            }
            aq[c] = __builtin_bit_cast(bf16x8, u);
        }
    }

    const unsigned short* kbg = wk  + (size_t)b * NTILE * TILE_USH;
    const unsigned short* vbg = wvt + (size_t)b * NTILE * TILE_USH;

    const int s_half = w4 >> 1;           // 0: K, 1: V
    const int s_sub  = w4 & 1;            // which 8KB of the 16KB half
    const unsigned short* sbase = s_half ? vbg : kbg;
    const int s_off  = s_sub * 4096 + lane * 8;

    float m_r = -__builtin_inff();
    float l_r = 0.f;
    f32x16 accO[4];
    #pragma unroll
    for (int dc = 0; dc < 4; ++dc)
        #pragma unroll
        for (int r = 0; r < 16; ++r) accO[dc][r] = 0.f;

    // ---- prologue: group g stages tile g into buf 0
    if (grp < ntiles) {
        const unsigned short* src = sbase + (size_t)grp * TILE_USH + s_off;
        unsigned short* dst = &smem[grp][0][s_half * 8192 + s_sub * 4096];
        #pragma unroll
        for (int j = 0; j < 8; ++j) load_lds16(src + j * 512, dst + j * 512);
    }
    __syncthreads();

    for (int i = 0; i < niter; ++i) {
        const int tile = 2 * i + grp;
        const int buf  = i & 1;
        const unsigned short* kl  = &smem[grp][buf][0];
        const unsigned short* vl2 = &smem[grp][buf][8192];

        // ---- issue stage of this group's next tile into the other buffer
        {
            const int tn = tile + 2;
            if (tn < ntiles) {
                const unsigned short* src = sbase + (size_t)tn * TILE_USH + s_off;
                unsigned short* dst = &smem[grp][buf ^ 1][s_half * 8192 + s_sub * 4096];
                #pragma unroll
                for (int j = 0; j < 8; ++j) load_lds16(src + j * 512, dst + j * 512);
            }
        }

        if (i < ng) {
            const int kv0 = tile * KVBLK;

            // ---- swapped QK^T: S^T[64k x 32q], A=K frags (LDS), B=Q regs
            f32x16 sA, sB;
            #pragma unroll
            for (int r = 0; r < 16; ++r) { sA[r] = 0.f; sB[r] = 0.f; }
            __builtin_amdgcn_s_setprio(1);
            #pragma unroll
            for (int c = 0; c < 8; ++c) {
                bf16x8 k0 = __builtin_bit_cast(bf16x8, *(const us8*)&kl[c * 512 + lane * 8]);
                sA = __builtin_amdgcn_mfma_f32_32x32x16_bf16(k0, aq[c], sA, 0, 0, 0);
            }
            #pragma unroll
            for (int c = 0; c < 8; ++c) {
                bf16x8 k1 = __builtin_bit_cast(bf16x8, *(const us8*)&kl[(8 + c) * 512 + lane * 8]);
                sB = __builtin_amdgcn_mfma_f32_32x32x16_bf16(k1, aq[c], sB, 0, 0, 0);
            }
            __builtin_amdgcn_s_setprio(0);

            // ---- mask (rows = k)
            if (uniform) {
                #pragma unroll
                for (int r = 0; r < 16; ++r) { sA[r] = 0.f; sB[r] = 0.f; }
            } else {
                const int lim0 = L - kv0 - 4 * hi;
                const int lim1 = lim0 - 32;
                #pragma unroll
                for (int r = 0; r < 16; ++r) {
                    const int rc = (r & 3) + 8 * (r >> 2);
                    sA[r] = (rc >= lim0) ? -__builtin_inff() : sA[r];
                    sB[r] = (rc >= lim1) ? -__builtin_inff() : sB[r];
                }
            }

            // ---- in-register softmax for q = lq
            float mx[8];
            #pragma unroll
            for (int i2 = 0; i2 < 8; ++i2)
                mx[i2] = fmaxf(fmaxf(sA[i2], sA[i2 + 8]), fmaxf(sB[i2], sB[i2 + 8]));
            #pragma unroll
            for (int i2 = 0; i2 < 4; ++i2) mx[i2] = fmaxf(mx[i2], mx[i2 + 4]);
            float pm = fmaxf(fmaxf(mx[0], mx[1]), fmaxf(mx[2], mx[3]));
            float pmax = fmaxf(pm, __shfl_xor(pm, 32));

            // T13: rescale only when some q-row got a new max
            if (__any(pmax > m_r)) {
                const float mnew = fmaxf(m_r, pmax);
                const float sc = __expf(m_r - mnew);
                m_r = mnew;
                l_r *= sc;
                #pragma unroll
                for (int r = 0; r < 16; ++r) {
                    const int src = ((r & 3) + 8 * (r >> 2) + 4 * hi) + (lane & 32);
                    const float scr = __shfl(sc, src);
                    accO[0][r] *= scr; accO[1][r] *= scr;
                    accO[2][r] *= scr; accO[3][r] *= scr;
                }
            }

            // ---- exp + row-sum
            float p0[16], p1[16];
            #pragma unroll
            for (int r = 0; r < 16; ++r) {
                p0[r] = __expf(sA[r] - m_r);
                p1[r] = __expf(sB[r] - m_r);
            }
            float sm[8];
            #pragma unroll
            for (int i2 = 0; i2 < 8; ++i2)
                sm[i2] = (p0[i2] + p0[i2 + 8]) + (p1[i2] + p1[i2 + 8]);
            #pragma unroll
            for (int i2 = 0; i2 < 4; ++i2) sm[i2] += sm[i2 + 4];
            float rsum = (sm[0] + sm[1]) + (sm[2] + sm[3]);
            rsum += __shfl_xor(rsum, 32);
            l_r += rsum;

            // ---- P -> bf16 packed words; half-exchange to build PV A-frags
            unsigned cw[16];
            #pragma unroll
            for (int i2 = 0; i2 < 8; ++i2) cw[i2] = cvt_pk_bf16(p0[2 * i2], p0[2 * i2 + 1]);
            #pragma unroll
            for (int i2 = 0; i2 < 8; ++i2) cw[8 + i2] = cvt_pk_bf16(p1[2 * i2], p1[2 * i2 + 1]);

            bf16x8 pa[4];
            #pragma unroll
            for (int ks = 0; ks < 4; ++ks) {
                const int a = 4 * ks;
                const unsigned u = hi ? cw[a]     : cw[a + 2];
                const unsigned v = hi ? cw[a + 1] : cw[a + 3];
                const unsigned up = __shfl_xor((int)u, 32);
                const unsigned vp = __shfl_xor((int)v, 32);
                u32x4 w;
                w[0] = hi ? up        : cw[a];
                w[1] = hi ? vp        : cw[a + 1];
                w[2] = hi ? cw[a + 2] : up;
                w[3] = hi ? cw[a + 3] : vp;
                pa[ks] = __builtin_bit_cast(bf16x8, w);
            }

            // ---- PV: O[32q x 128d] += P(32x64) . V(64x128)
            __builtin_amdgcn_s_setprio(1);
            #pragma unroll
            for (int dc = 0; dc < 4; ++dc) {
                #pragma unroll
                for (int ks = 0; ks < 4; ++ks) {
                    bf16x8 bv = __builtin_bit_cast(bf16x8,
                        *(const us8*)&vl2[(ks * 4 + dc) * 512 + lane * 8]);
                    accO[dc] = __builtin_amdgcn_mfma_f32_32x32x16_bf16(pa[ks], bv, accO[dc], 0, 0, 0);
                }
            }
            __builtin_amdgcn_s_setprio(0);
        }

        __syncthreads();   // drains stage issues (vmcnt 0) + fences buffer reuse
    }

    // ---- merge epilogue: group1 -> LDS, group0 combines + stores
    float* accb = (float*)&smem[0][0][0];            // 64 KB: [w4][j0..15][lane] f4
    float* mlb  = (float*)&smem[1][0][0];            // m[128], l[128]
    if (grp == 1) {
        #pragma unroll
        for (int dc = 0; dc < 4; ++dc) {
            #pragma unroll
            for (int q4 = 0; q4 < 4; ++q4) {
                f4 v;
                #pragma unroll
                for (int c = 0; c < 4; ++c) v[c] = accO[dc][q4 * 4 + c];
                *(f4*)&accb[(((w4 * 16 + dc * 4 + q4) * 64) + lane) * 4] = v;
            }
        }
        if (hi == 0) {
            mlb[w4 * 32 + lq]       = m_r;
            mlb[128 + w4 * 32 + lq] = l_r;
        }
    }
    __syncthreads();
    if (grp == 0) {
        const float m1 = mlb[w4 * 32 + lq];
        const float l1 = mlb[128 + w4 * 32 + lq];
        const float m  = fmaxf(m_r, m1);
        const float a0 = __expf(m_r - m), a1 = __expf(m1 - m);
        const float linv = 1.0f / (a0 * l_r + a1 * l1);
        const float s0v = a0 * linv, s1v = a1 * linv;
        float* ob = og + (size_t)(b * NQ + q0 + w4 * 32) * ND;
        #pragma unroll
        for (int dc = 0; dc < 4; ++dc) {
            #pragma unroll
            for (int q4 = 0; q4 < 4; ++q4) {
                f4 o1 = *(const f4*)&accb[(((w4 * 16 + dc * 4 + q4) * 64) + lane) * 4];
                #pragma unroll
                for (int c = 0; c < 4; ++c) {
                    const int r = q4 * 4 + c;
                    const int row = c + 8 * q4 + 4 * hi;
                    const float s0r = __shfl(s0v, row + (lane & 32));
                    const float s1r = __shfl(s1v, row + (lane & 32));
                    ob[(size_t)row * ND + dc * 32 + lq] = accO[dc][r] * s0r + o1[c] * s1r;
                }
            }
        }
    }
}

// ---------------------------------------------------------------------------
// Fallback (R1 kernel): used only if ws_size < 16 MB
// ---------------------------------------------------------------------------
__global__ __launch_bounds__(256, 2)
void attn_fused(const float* __restrict__ qg, const float* __restrict__ kg,
                const float* __restrict__ vg, const int* __restrict__ vlen,
                float* __restrict__ og)
{
    const int b    = blockIdx.y;
    const int q0   = blockIdx.x * 64;
    const int tid  = threadIdx.x;
    const int wid  = tid >> 6;
    const int lane = tid & 63;
    const int lrow = lane & 15;
    const int lgrp = lane >> 4;

    const int L = vlen[b];
    const bool uniform = (L <= 0);
    const int Leff = uniform ? NK : L;
    const int nt32 = (Leff + 31) / 32;

    __shared__ __align__(16) unsigned short kt[32 * 136];
    __shared__ __align__(16) unsigned short vt[128 * 40];
    __shared__ __align__(16) float pt[4][16 * 36];

    bf16x8 aqf[4];
    {
        const float* qp = qg + (size_t)(b * NQ + q0 + wid * 16 + lrow) * ND + lgrp * 8;
        #pragma unroll
        for (int c = 0; c < 4; ++c) {
            f4 f0 = *(const f4*)(qp + c * 32);
            f4 f1 = *(const f4*)(qp + c * 32 + 4);
            us8 u;
            #pragma unroll
            for (int i = 0; i < 4; ++i) {
                u[i]     = f2bf(f0[i] * SCALE);
                u[i + 4] = f2bf(f1[i] * SCALE);
            }
            aqf[c] = __builtin_bit_cast(bf16x8, u);
        }
    }

    float m_r[4], l_r[4];
    f4 accO[8];
    #pragma unroll
    for (int r = 0; r < 4; ++r) { m_r[r] = -__builtin_inff(); l_r[r] = 0.f; }
    #pragma unroll
    for (int dc = 0; dc < 8; ++dc) accO[dc] = splat4(0.f);

    for (int t = 0; t < nt32; ++t) {
        const int kv0 = t * 32;
        __syncthreads();
        {
            const int r  = tid >> 3;
            const int c0 = (tid & 7) * 16;
            const float* gp = kg + (size_t)(b * NK + kv0 + r) * ND + c0;
            f4 f0 = *(const f4*)(gp);
            f4 f1 = *(const f4*)(gp + 4);
            f4 f2 = *(const f4*)(gp + 8);
            f4 f3 = *(const f4*)(gp + 12);
            us8 w0, w1;
            #pragma unroll
            for (int i = 0; i < 4; ++i) {
                w0[i]     = f2bf(f0[i]);
                w0[i + 4] = f2bf(f1[i]);
                w1[i]     = f2bf(f2[i]);
                w1[i + 4] = f2bf(f3[i]);
            }
            unsigned short* dst = &kt[r * 136 + c0];
            *(us8*)(dst)     = w0;
            *(us8*)(dst + 8) = w1;
        }
        {
            const int d  = tid & 127;
            const int g2 = tid >> 7;
            const float* gp = vg + (size_t)(b * NK + kv0 + g2 * 16) * ND + d;
            us8 w0, w1;
            #pragma unroll
            for (int j = 0; j < 8; ++j) {
                w0[j] = f2bf(gp[(size_t)j * ND]);
                w1[j] = f2bf(gp[(size_t)(j + 8) * ND]);
            }
            unsigned short* dst = &vt[d * 40 + g2 * 16];
            *(us8*)(dst)     = w0;
            *(us8*)(dst + 8) = w1;
        }
        __syncthreads();

        f4 s0 = splat4(0.f), s1 = splat4(0.f);
        #pragma unroll
        for (int c = 0; c < 4; ++c) {
            bf16x8 bk0 = __builtin_bit_cast(bf16x8,
                *(const us8*)&kt[lrow * 136 + c * 32 + lgrp * 8]);
            s0 = __builtin_amdgcn_mfma_f32_16x16x32_bf16(aqf[c], bk0, s0, 0, 0, 0);
            bf16x8 bk1 = __builtin_bit_cast(bf16x8,
                *(const us8*)&kt[(16 + lrow) * 136 + c * 32 + lgrp * 8]);
            s1 = __builtin_amdgcn_mfma_f32_16x16x32_bf16(aqf[c], bk1, s1, 0, 0, 0);
        }

        const int col0 = kv0 + lrow;
        if (uniform) {
            s0 = splat4(0.f);
            s1 = splat4(0.f);
        } else {
            if (col0 >= L)      s0 = splat4(-__builtin_inff());
            if (col0 + 16 >= L) s1 = splat4(-__builtin_inff());
        }

        float pm[4];
        #pragma unroll
        for (int r = 0; r < 4; ++r) pm[r] = fmaxf(s0[r], s1[r]);
        #pragma unroll
        for (int off = 8; off > 0; off >>= 1) {
            #pragma unroll
            for (int r = 0; r < 4; ++r)
                pm[r] = fmaxf(pm[r], __shfl_xor(pm[r], off));
        }
        float pr0[4], pr1[4], rs[4], sc[4];
        #pragma unroll
        for (int r = 0; r < 4; ++r) {
            float mn = fmaxf(m_r[r], pm[r]);
            sc[r]  = __expf(m_r[r] - mn);
            m_r[r] = mn;
            pr0[r] = __expf(s0[r] - mn);
            pr1[r] = __expf(s1[r] - mn);
            rs[r]  = pr0[r] + pr1[r];
        }
        #pragma unroll
        for (int off = 8; off > 0; off >>= 1) {
            #pragma unroll
            for (int r = 0; r < 4; ++r)
                rs[r] += __shfl_xor(rs[r], off);
        }
        #pragma unroll
        for (int r = 0; r < 4; ++r) l_r[r] = l_r[r] * sc[r] + rs[r];
        #pragma unroll
        for (int dc = 0; dc < 8; ++dc) {
            #pragma unroll
            for (int r = 0; r < 4; ++r) accO[dc][r] *= sc[r];
        }

        float* pw = pt[wid];
        #pragma unroll
        for (int r = 0; r < 4; ++r) {
            pw[(lgrp * 4 + r) * 36 + lrow]      = pr0[r];
            pw[(lgrp * 4 + r) * 36 + 16 + lrow] = pr1[r];
        }
        asm volatile("s_waitcnt lgkmcnt(0)" ::: "memory");
        f4 a0 = *(const f4*)&pw[lrow * 36 + lgrp * 8];
        f4 a1 = *(const f4*)&pw[lrow * 36 + lgrp * 8 + 4];
        us8 au;
        #pragma unroll
        for (int i = 0; i < 4; ++i) { au[i] = f2bf(a0[i]); au[i + 4] = f2bf(a1[i]); }
        bf16x8 ap = __builtin_bit_cast(bf16x8, au);

        #pragma unroll
        for (int dc = 0; dc < 8; ++dc) {
            bf16x8 bv = __builtin_bit_cast(bf16x8,
                *(const us8*)&vt[(dc * 16 + lrow) * 40 + lgrp * 8]);
            accO[dc] = __builtin_amdgcn_mfma_f32_16x16x32_bf16(ap, bv, accO[dc], 0, 0, 0);
        }
    }

    float inv[4];
    #pragma unroll
    for (int r = 0; r < 4; ++r) inv[r] = 1.0f / l_r[r];
    float* op = og + (size_t)(b * NQ + q0 + wid * 16) * ND;
    #pragma unroll
    for (int dc = 0; dc < 8; ++dc) {
        #pragma unroll
        for (int r = 0; r < 4; ++r)
            op[(lgrp * 4 + r) * ND + dc * 16 + lrow] = accO[dc][r] * inv[r];
    }
}

extern "C" void kernel_launch(void* const* d_in, const int* in_sizes, int n_in,
                              void* d_out, int out_size, void* d_ws, size_t ws_size,
                              hipStream_t stream) {
    (void)in_sizes; (void)n_in; (void)out_size;
    const float* q  = (const float*)d_in[0];
    const float* k  = (const float*)d_in[1];
    const float* v  = (const float*)d_in[2];
    const int*   vl = (const int*)d_in[3];
    float* out = (float*)d_out;

    const size_t half = (size_t)NB * NK * ND * sizeof(unsigned short); // 8 MB
    if (ws_size >= 2 * half) {
        unsigned short* wk  = (unsigned short*)d_ws;
        unsigned short* wvt = wk + (size_t)NB * NK * ND;
        hipLaunchKernelGGL(prep_kv4, dim3(NTILE, NB), dim3(256), 0, stream, k, v, wk, wvt);
        hipLaunchKernelGGL(attn_fused6, dim3((NQ / 128) * NB), dim3(512), 0, stream,
                           q, vl, wk, wvt, out);
    } else {
        hipLaunchKernelGGL(attn_fused, dim3(NQ / 64, NB), dim3(256), 0, stream,
                           q, k, v, vl, out);
    }
}

// Round 7
// 63.390 us; speedup vs baseline: 3.4038x; 1.0410x over previous
//
#include <hip/hip_runtime.h>

// Problem constants (reference: B=16, Q=2048, K=2048, D=128, fp32, NEG=-1e6)
constexpr int NB = 16;
constexpr int NQ = 2048;
constexpr int NK = 2048;
constexpr int ND = 128;
constexpr int KVBLK = 64;                 // kv per tile
constexpr int NTILE = NK / KVBLK;         // 32
constexpr int TILE_USH = KVBLK * ND;      // 8192 ushorts = 16KB per tile
constexpr float SCALE = 0.08838834764831844f; // 1/sqrt(128)

typedef __attribute__((ext_vector_type(4))) float f4;
typedef __attribute__((ext_vector_type(16))) float f32x16;
typedef __attribute__((ext_vector_type(8))) unsigned short us8;
typedef __attribute__((ext_vector_type(8))) __bf16 bf16x8;
typedef __attribute__((ext_vector_type(4))) unsigned int u32x4;

static __device__ __forceinline__ unsigned short f2bf(float f) {
    unsigned u = __builtin_bit_cast(unsigned, f);
    u += 0x7fffu + ((u >> 16) & 1u);
    return (unsigned short)(u >> 16);
}
static __device__ __forceinline__ f4 splat4(float x) { f4 r = {x,x,x,x}; return r; }

static __device__ __forceinline__ void load_lds16(const unsigned short* g, unsigned short* l) {
    __builtin_amdgcn_global_load_lds(
        (const __attribute__((address_space(1))) void*)g,
        (__attribute__((address_space(3))) void*)l,
        16, 0, 0);
}

static __device__ __forceinline__ unsigned cvt_pk_bf16(float lo, float hi) {
    unsigned r;
    asm("v_cvt_pk_bf16_f32 %0, %1, %2" : "=v"(r) : "v"(lo), "v"(hi));
    return r;
}

// ---------------------------------------------------------------------------
// Prep: per (batch, kv-tile=64) write K and V in lane-linear 32x32-MFMA
// fragment order (unchanged from R5/R6):
//  K  (kv,d): off = ((kv>>5)*8 + (d>>4))*512 + ((d>>3)&1)*256 + (kv&31)*8 + (d&7)
//  V  (kv,d): off = ((kv>>4)*4 + (d>>5))*512 + ((kv>>3)&1)*256 + (d&31)*8 + (kv&7)
// grid (NTILE, NB), 256 threads
// ---------------------------------------------------------------------------
__global__ __launch_bounds__(256)
void prep_kv4(const float* __restrict__ kg, const float* __restrict__ vg,
              unsigned short* __restrict__ wk, unsigned short* __restrict__ wvt)
{
    const int b   = blockIdx.y;
    const int t   = blockIdx.x;
    const int kv0 = t * KVBLK;
    const int t0  = threadIdx.x;

    __shared__ __align__(16) unsigned short vl[64 * 136];

    {
        const int kv = t0 >> 2;
        const int c  = t0 & 3;
        const float* gp = kg + (size_t)(b * NK + kv0 + kv) * ND + c * 32;
        unsigned short* ob = wk + (size_t)(b * NTILE + t) * TILE_USH;
        #pragma unroll
        for (int g = 0; g < 4; ++g) {
            f4 f0 = *(const f4*)(gp + g * 8);
            f4 f1 = *(const f4*)(gp + g * 8 + 4);
            us8 w;
            #pragma unroll
            for (int i = 0; i < 4; ++i) { w[i] = f2bf(f0[i]); w[i+4] = f2bf(f1[i]); }
            const int d0 = c * 32 + g * 8;
            const int f  = (kv >> 5) * 8 + (d0 >> 4);
            const int off = f * 512 + ((d0 >> 3) & 1) * 256 + (kv & 31) * 8;
            *(us8*)(ob + off) = w;
        }
    }
    {
        const int kv = t0 >> 2;
        const int d0 = (t0 & 3) * 32;
        const float* gp = vg + (size_t)(b * NK + kv0 + kv) * ND + d0;
        unsigned short* lb = &vl[kv * 136 + d0];
        #pragma unroll
        for (int g = 0; g < 4; ++g) {
            f4 f0 = *(const f4*)(gp + g * 8);
            f4 f1 = *(const f4*)(gp + g * 8 + 4);
            us8 w;
            #pragma unroll
            for (int i = 0; i < 4; ++i) { w[i] = f2bf(f0[i]); w[i+4] = f2bf(f1[i]); }
            *(us8*)(lb + g * 8) = w;
        }
    }
    __syncthreads();
    {
        unsigned short* ob = wvt + (size_t)(b * NTILE + t) * TILE_USH;
        #pragma unroll
        for (int iter = 0; iter < 4; ++iter) {
            const int cid = iter * 256 + t0;
            const int f   = cid >> 6;
            const int l   = cid & 63;
            const int kb  = (f >> 2) * 16 + (l >> 5) * 8;
            const int d   = (f & 3) * 32 + (l & 31);
            us8 w;
            #pragma unroll
            for (int j = 0; j < 8; ++j) w[j] = vl[(kb + j) * 136 + d];
            *(us8*)(ob + cid * 8) = w;
        }
    }
}

// ---------------------------------------------------------------------------
// Fused attention v7: R6 structure + issue-early register staging.
// All K-frag ds_reads enqueued up front, QK from regs, then all V-frag
// ds_reads enqueued, softmax overlaps their drain, PV from regs.
// ---------------------------------------------------------------------------
__global__ __launch_bounds__(512, 2)
void attn_fused7(const float* __restrict__ qg, const int* __restrict__ vlen,
                 const unsigned short* __restrict__ wk,
                 const unsigned short* __restrict__ wvt,
                 float* __restrict__ og)
{
    const int bid = blockIdx.x;
    const int b   = bid & 15;      // XCD x hosts batches {x, x+8}: KV L2-resident
    const int qc  = bid >> 4;
    const int q0  = qc * 128;

    const int tid  = threadIdx.x;
    const int wid  = tid >> 6;
    const int grp  = wid >> 2;     // KV-split group 0/1
    const int w4   = wid & 3;      // q-chunk within block (32 rows each)
    const int lane = tid & 63;
    const int lq   = lane & 31;
    const int hi   = lane >> 5;

    const int L = vlen[b];
    const bool uniform = (L <= 0);
    const int Leff = uniform ? NK : L;
    const int ntiles = (Leff + KVBLK - 1) / KVBLK;
    const int ng    = (ntiles + 1 - grp) >> 1;
    const int niter = (ntiles + 1) >> 1;

    __shared__ __align__(16) unsigned short smem[2][2][2 * TILE_USH];

    // ---- Q fragments (B-operand), scaled
    bf16x8 aq[8];
    {
        const float* qp = qg + (size_t)(b * NQ + q0 + w4 * 32 + lq) * ND + hi * 8;
        #pragma unroll
        for (int c = 0; c < 8; ++c) {
            f4 f0 = *(const f4*)(qp + c * 16);
            f4 f1 = *(const f4*)(qp + c * 16 + 4);
            us8 u;
            #pragma unroll
            for (int i = 0; i < 4; ++i) {
                u[i]     = f2bf(f0[i] * SCALE);
                u[i + 4] = f2bf(f1[i] * SCALE);
            }
            aq[c] = __builtin_bit_cast(bf16x8, u);
        }
    }

    const unsigned short* kbg = wk  + (size_t)b * NTILE * TILE_USH;
    const unsigned short* vbg = wvt + (size_t)b * NTILE * TILE_USH;

    const int s_half = w4 >> 1;
    const int s_sub  = w4 & 1;
    const unsigned short* sbase = s_half ? vbg : kbg;
    const int s_off  = s_sub * 4096 + lane * 8;

    float m_r = -__builtin_inff();
    float l_r = 0.f;
    f32x16 accO[4];
    #pragma unroll
    for (int dc = 0; dc < 4; ++dc)
        #pragma unroll
        for (int r = 0; r < 16; ++r) accO[dc][r] = 0.f;

    // ---- prologue: group g stages tile g into buf 0
    if (grp < ntiles) {
        const unsigned short* src = sbase + (size_t)grp * TILE_USH + s_off;
        unsigned short* dst = &smem[grp][0][s_half * 8192 + s_sub * 4096];
        #pragma unroll
        for (int j = 0; j < 8; ++j) load_lds16(src + j * 512, dst + j * 512);
    }
    __syncthreads();

    for (int i = 0; i < niter; ++i) {
        const int tile = 2 * i + grp;
        const int buf  = i & 1;
        const unsigned short* kl  = &smem[grp][buf][0];
        const unsigned short* vl2 = &smem[grp][buf][8192];

        // ---- issue stage of this group's next tile into the other buffer
        {
            const int tn = tile + 2;
            if (tn < ntiles) {
                const unsigned short* src = sbase + (size_t)tn * TILE_USH + s_off;
                unsigned short* dst = &smem[grp][buf ^ 1][s_half * 8192 + s_sub * 4096];
                #pragma unroll
                for (int j = 0; j < 8; ++j) load_lds16(src + j * 512, dst + j * 512);
            }
        }

        if (i < ng) {
            const int kv0 = tile * KVBLK;

            // ---- enqueue ALL K-frag reads to registers up front
            us8 kf[16];
            #pragma unroll
            for (int c = 0; c < 16; ++c)
                kf[c] = *(const us8*)&kl[c * 512 + lane * 8];

            // ---- QK^T from regs: two independent MFMA chains interleaved
            f32x16 sA, sB;
            #pragma unroll
            for (int r = 0; r < 16; ++r) { sA[r] = 0.f; sB[r] = 0.f; }
            __builtin_amdgcn_s_setprio(1);
            #pragma unroll
            for (int c = 0; c < 8; ++c) {
                sA = __builtin_amdgcn_mfma_f32_32x32x16_bf16(
                    __builtin_bit_cast(bf16x8, kf[c]), aq[c], sA, 0, 0, 0);
                sB = __builtin_amdgcn_mfma_f32_32x32x16_bf16(
                    __builtin_bit_cast(bf16x8, kf[8 + c]), aq[c], sB, 0, 0, 0);
            }
            __builtin_amdgcn_s_setprio(0);
            // keep vf loads from being hoisted above QK (VGPR peak control)
            __builtin_amdgcn_sched_barrier(0);

            // ---- enqueue ALL V-frag reads; drain hides under softmax below
            us8 vf[16];
            #pragma unroll
            for (int f = 0; f < 16; ++f)
                vf[f] = *(const us8*)&vl2[f * 512 + lane * 8];

            // ---- mask (rows = k)
            if (uniform) {
                #pragma unroll
                for (int r = 0; r < 16; ++r) { sA[r] = 0.f; sB[r] = 0.f; }
            } else {
                const int lim0 = L - kv0 - 4 * hi;
                const int lim1 = lim0 - 32;
                #pragma unroll
                for (int r = 0; r < 16; ++r) {
                    const int rc = (r & 3) + 8 * (r >> 2);
                    sA[r] = (rc >= lim0) ? -__builtin_inff() : sA[r];
                    sB[r] = (rc >= lim1) ? -__builtin_inff() : sB[r];
                }
            }

            // ---- in-register softmax for q = lq
            float mx[8];
            #pragma unroll
            for (int i2 = 0; i2 < 8; ++i2)
                mx[i2] = fmaxf(fmaxf(sA[i2], sA[i2 + 8]), fmaxf(sB[i2], sB[i2 + 8]));
            #pragma unroll
            for (int i2 = 0; i2 < 4; ++i2) mx[i2] = fmaxf(mx[i2], mx[i2 + 4]);
            float pm = fmaxf(fmaxf(mx[0], mx[1]), fmaxf(mx[2], mx[3]));
            float pmax = fmaxf(pm, __shfl_xor(pm, 32));

            // T13: rescale only when some q-row got a new max
            if (__any(pmax > m_r)) {
                const float mnew = fmaxf(m_r, pmax);
                const float sc = __expf(m_r - mnew);
                m_r = mnew;
                l_r *= sc;
                #pragma unroll
                for (int r = 0; r < 16; ++r) {
                    const int src = ((r & 3) + 8 * (r >> 2) + 4 * hi) + (lane & 32);
                    const float scr = __shfl(sc, src);
                    accO[0][r] *= scr; accO[1][r] *= scr;
                    accO[2][r] *= scr; accO[3][r] *= scr;
                }
            }

            // ---- exp + row-sum
            float p0[16], p1[16];
            #pragma unroll
            for (int r = 0; r < 16; ++r) {
                p0[r] = __expf(sA[r] - m_r);
                p1[r] = __expf(sB[r] - m_r);
            }
            float sm[8];
            #pragma unroll
            for (int i2 = 0; i2 < 8; ++i2)
                sm[i2] = (p0[i2] + p0[i2 + 8]) + (p1[i2] + p1[i2 + 8]);
            #pragma unroll
            for (int i2 = 0; i2 < 4; ++i2) sm[i2] += sm[i2 + 4];
            float rsum = (sm[0] + sm[1]) + (sm[2] + sm[3]);
            rsum += __shfl_xor(rsum, 32);
            l_r += rsum;

            // ---- P -> bf16 packed words; half-exchange to build PV A-frags
            unsigned cw[16];
            #pragma unroll
            for (int i2 = 0; i2 < 8; ++i2) cw[i2] = cvt_pk_bf16(p0[2 * i2], p0[2 * i2 + 1]);
            #pragma unroll
            for (int i2 = 0; i2 < 8; ++i2) cw[8 + i2] = cvt_pk_bf16(p1[2 * i2], p1[2 * i2 + 1]);

            bf16x8 pa[4];
            #pragma unroll
            for (int ks = 0; ks < 4; ++ks) {
                const int a = 4 * ks;
                const unsigned u = hi ? cw[a]     : cw[a + 2];
                const unsigned v = hi ? cw[a + 1] : cw[a + 3];
                const unsigned up = __shfl_xor((int)u, 32);
                const unsigned vp = __shfl_xor((int)v, 32);
                u32x4 w;
                w[0] = hi ? up        : cw[a];
                w[1] = hi ? vp        : cw[a + 1];
                w[2] = hi ? cw[a + 2] : up;
                w[3] = hi ? cw[a + 3] : vp;
                pa[ks] = __builtin_bit_cast(bf16x8, w);
            }

            // ---- PV from regs: O[32q x 128d] += P(32x64) . V(64x128)
            __builtin_amdgcn_s_setprio(1);
            #pragma unroll
            for (int dc = 0; dc < 4; ++dc) {
                #pragma unroll
                for (int ks = 0; ks < 4; ++ks) {
                    accO[dc] = __builtin_amdgcn_mfma_f32_32x32x16_bf16(
                        pa[ks], __builtin_bit_cast(bf16x8, vf[ks * 4 + dc]), accO[dc], 0, 0, 0);
                }
            }
            __builtin_amdgcn_s_setprio(0);
        }

        __syncthreads();   // drains stage issues + fences buffer reuse
    }

    // ---- merge epilogue: group1 -> LDS, group0 combines + stores
    float* accb = (float*)&smem[0][0][0];
    float* mlb  = (float*)&smem[1][0][0];
    if (grp == 1) {
        #pragma unroll
        for (int dc = 0; dc < 4; ++dc) {
            #pragma unroll
            for (int q4 = 0; q4 < 4; ++q4) {
                f4 v;
                #pragma unroll
                for (int c = 0; c < 4; ++c) v[c] = accO[dc][q4 * 4 + c];
                *(f4*)&accb[(((w4 * 16 + dc * 4 + q4) * 64) + lane) * 4] = v;
            }
        }
        if (hi == 0) {
            mlb[w4 * 32 + lq]       = m_r;
            mlb[128 + w4 * 32 + lq] = l_r;
        }
    }
    __syncthreads();
    if (grp == 0) {
        const float m1 = mlb[w4 * 32 + lq];
        const float l1 = mlb[128 + w4 * 32 + lq];
        const float m  = fmaxf(m_r, m1);
        const float a0 = __expf(m_r - m), a1 = __expf(m1 - m);
        const float linv = 1.0f / (a0 * l_r + a1 * l1);
        const float s0v = a0 * linv, s1v = a1 * linv;
        float* ob = og + (size_t)(b * NQ + q0 + w4 * 32) * ND;
        #pragma unroll
        for (int dc = 0; dc < 4; ++dc) {
            #pragma unroll
            for (int q4 = 0; q4 < 4; ++q4) {
                f4 o1 = *(const f4*)&accb[(((w4 * 16 + dc * 4 + q4) * 64) + lane) * 4];
                #pragma unroll
                for (int c = 0; c < 4; ++c) {
                    const int r = q4 * 4 + c;
                    const int row = c + 8 * q4 + 4 * hi;
                    const float s0r = __shfl(s0v, row + (lane & 32));
                    const float s1r = __shfl(s1v, row + (lane & 32));
                    ob[(size_t)row * ND + dc * 32 + lq] = accO[dc][r] * s0r + o1[c] * s1r;
                }
            }
        }
    }
}

// ---------------------------------------------------------------------------
// Fallback (R1 kernel): used only if ws_size < 16 MB
// ---------------------------------------------------------------------------
__global__ __launch_bounds__(256, 2)
void attn_fused(const float* __restrict__ qg, const float* __restrict__ kg,
                const float* __restrict__ vg, const int* __restrict__ vlen,
                float* __restrict__ og)
{
    const int b    = blockIdx.y;
    const int q0   = blockIdx.x * 64;
    const int tid  = threadIdx.x;
    const int wid  = tid >> 6;
    const int lane = tid & 63;
    const int lrow = lane & 15;
    const int lgrp = lane >> 4;

    const int L = vlen[b];
    const bool uniform = (L <= 0);
    const int Leff = uniform ? NK : L;
    const int nt32 = (Leff + 31) / 32;

    __shared__ __align__(16) unsigned short kt[32 * 136];
    __shared__ __align__(16) unsigned short vt[128 * 40];
    __shared__ __align__(16) float pt[4][16 * 36];

    bf16x8 aqf[4];
    {
        const float* qp = qg + (size_t)(b * NQ + q0 + wid * 16 + lrow) * ND + lgrp * 8;
        #pragma unroll
        for (int c = 0; c < 4; ++c) {
            f4 f0 = *(const f4*)(qp + c * 32);
            f4 f1 = *(const f4*)(qp + c * 32 + 4);
            us8 u;
            #pragma unroll
            for (int i = 0; i < 4; ++i) {
                u[i]     = f2bf(f0[i] * SCALE);
                u[i + 4] = f2bf(f1[i] * SCALE);
            }
            aqf[c] = __builtin_bit_cast(bf16x8, u);
        }
    }

    float m_r[4], l_r[4];
    f4 accO[8];
    #pragma unroll
    for (int r = 0; r < 4; ++r) { m_r[r] = -__builtin_inff(); l_r[r] = 0.f; }
    #pragma unroll
    for (int dc = 0; dc < 8; ++dc) accO[dc] = splat4(0.f);

    for (int t = 0; t < nt32; ++t) {
        const int kv0 = t * 32;
        __syncthreads();
        {
            const int r  = tid >> 3;
            const int c0 = (tid & 7) * 16;
            const float* gp = kg + (size_t)(b * NK + kv0 + r) * ND + c0;
            f4 f0 = *(const f4*)(gp);
            f4 f1 = *(const f4*)(gp + 4);
            f4 f2 = *(const f4*)(gp + 8);
            f4 f3 = *(const f4*)(gp + 12);
            us8 w0, w1;
            #pragma unroll
            for (int i = 0; i < 4; ++i) {
                w0[i]     = f2bf(f0[i]);
                w0[i + 4] = f2bf(f1[i]);
                w1[i]     = f2bf(f2[i]);
                w1[i + 4] = f2bf(f3[i]);
            }
            unsigned short* dst = &kt[r * 136 + c0];
            *(us8*)(dst)     = w0;
            *(us8*)(dst + 8) = w1;
        }
        {
            const int d  = tid & 127;
            const int g2 = tid >> 7;
            const float* gp = vg + (size_t)(b * NK + kv0 + g2 * 16) * ND + d;
            us8 w0, w1;
            #pragma unroll
            for (int j = 0; j < 8; ++j) {
                w0[j] = f2bf(gp[(size_t)j * ND]);
                w1[j] = f2bf(gp[(size_t)(j + 8) * ND]);
            }
            unsigned short* dst = &vt[d * 40 + g2 * 16];
            *(us8*)(dst)     = w0;
            *(us8*)(dst + 8) = w1;
        }
        __syncthreads();

        f4 s0 = splat4(0.f), s1 = splat4(0.f);
        #pragma unroll
        for (int c = 0; c < 4; ++c) {
            bf16x8 bk0 = __builtin_bit_cast(bf16x8,
                *(const us8*)&kt[lrow * 136 + c * 32 + lgrp * 8]);
            s0 = __builtin_amdgcn_mfma_f32_16x16x32_bf16(aqf[c], bk0, s0, 0, 0, 0);
            bf16x8 bk1 = __builtin_bit_cast(bf16x8,
                *(const us8*)&kt[(16 + lrow) * 136 + c * 32 + lgrp * 8]);
            s1 = __builtin_amdgcn_mfma_f32_16x16x32_bf16(aqf[c], bk1, s1, 0, 0, 0);
        }

        const int col0 = kv0 + lrow;
        if (uniform) {
            s0 = splat4(0.f);
            s1 = splat4(0.f);
        } else {
            if (col0 >= L)      s0 = splat4(-__builtin_inff());
            if (col0 + 16 >= L) s1 = splat4(-__builtin_inff());
        }

        float pm[4];
        #pragma unroll
        for (int r = 0; r < 4; ++r) pm[r] = fmaxf(s0[r], s1[r]);
        #pragma unroll
        for (int off = 8; off > 0; off >>= 1) {
            #pragma unroll
            for (int r = 0; r < 4; ++r)
                pm[r] = fmaxf(pm[r], __shfl_xor(pm[r], off));
        }
        float pr0[4], pr1[4], rs[4], sc[4];
        #pragma unroll
        for (int r = 0; r < 4; ++r) {
            float mn = fmaxf(m_r[r], pm[r]);
            sc[r]  = __expf(m_r[r] - mn);
            m_r[r] = mn;
            pr0[r] = __expf(s0[r] - mn);
            pr1[r] = __expf(s1[r] - mn);
            rs[r]  = pr0[r] + pr1[r];
        }
        #pragma unroll
        for (int off = 8; off > 0; off >>= 1) {
            #pragma unroll
            for (int r = 0; r < 4; ++r)
                rs[r] += __shfl_xor(rs[r], off);
        }
        #pragma unroll
        for (int r = 0; r < 4; ++r) l_r[r] = l_r[r] * sc[r] + rs[r];
        #pragma unroll
        for (int dc = 0; dc < 8; ++dc) {
            #pragma unroll
            for (int r = 0; r < 4; ++r) accO[dc][r] *= sc[r];
        }

        float* pw = pt[wid];
        #pragma unroll
        for (int r = 0; r < 4; ++r) {
            pw[(lgrp * 4 + r) * 36 + lrow]      = pr0[r];
            pw[(lgrp * 4 + r) * 36 + 16 + lrow] = pr1[r];
        }
        asm volatile("s_waitcnt lgkmcnt(0)" ::: "memory");
        f4 a0 = *(const f4*)&pw[lrow * 36 + lgrp * 8];
        f4 a1 = *(const f4*)&pw[lrow * 36 + lgrp * 8 + 4];
        us8 au;
        #pragma unroll
        for (int i = 0; i < 4; ++i) { au[i] = f2bf(a0[i]); au[i + 4] = f2bf(a1[i]); }
        bf16x8 ap = __builtin_bit_cast(bf16x8, au);

        #pragma unroll
        for (int dc = 0; dc < 8; ++dc) {
            bf16x8 bv = __builtin_bit_cast(bf16x8,
                *(const us8*)&vt[(dc * 16 + lrow) * 40 + lgrp * 8]);
            accO[dc] = __builtin_amdgcn_mfma_f32_16x16x32_bf16(ap, bv, accO[dc], 0, 0, 0);
        }
    }

    float inv[4];
    #pragma unroll
    for (int r = 0; r < 4; ++r) inv[r] = 1.0f / l_r[r];
    float* op = og + (size_t)(b * NQ + q0 + wid * 16) * ND;
    #pragma unroll
    for (int dc = 0; dc < 8; ++dc) {
        #pragma unroll
        for (int r = 0; r < 4; ++r)
            op[(lgrp * 4 + r) * ND + dc * 16 + lrow] = accO[dc][r] * inv[r];
    }
}

extern "C" void kernel_launch(void* const* d_in, const int* in_sizes, int n_in,
                              void* d_out, int out_size, void* d_ws, size_t ws_size,
                              hipStream_t stream) {
    (void)in_sizes; (void)n_in; (void)out_size;
    const float* q  = (const float*)d_in[0];
    const float* k  = (const float*)d_in[1];
    const float* v  = (const float*)d_in[2];
    const int*   vl = (const int*)d_in[3];
    float* out = (float*)d_out;

    const size_t half = (size_t)NB * NK * ND * sizeof(unsigned short); // 8 MB
    if (ws_size >= 2 * half) {
        unsigned short* wk  = (unsigned short*)d_ws;
        unsigned short* wvt = wk + (size_t)NB * NK * ND;
        hipLaunchKernelGGL(prep_kv4, dim3(NTILE, NB), dim3(256), 0, stream, k, v, wk, wvt);
        hipLaunchKernelGGL(attn_fused7, dim3((NQ / 128) * NB), dim3(512), 0, stream,
                           q, vl, wk, wvt, out);
    } else {
        hipLaunchKernelGGL(attn_fused, dim3(NQ / 64, NB), dim3(256), 0, stream,
                           q, k, v, vl, out);
    }
}